// Round 1
// baseline (2342.877 us; speedup 1.0000x reference)
//
#include <hip/hip_runtime.h>

#define NN 100000
#define DD 128
#define CC 64

// ---------------- degree count ----------------
__global__ __launch_bounds__(256) void deg_kernel(const int* __restrict__ ei,
                                                  float* __restrict__ deg, int E) {
    int e = blockIdx.x * 256 + threadIdx.x;
    if (e < E) unsafeAtomicAdd(&deg[ei[E + e]], 1.0f);
}

// ---------------- scatter-add aggregation ----------------
// thread -> (edge, dim): wave of 64 lanes covers 64 consecutive dims of one edge
// => scalar (uniform) edge-index loads, coalesced 256B gather + 256B atomic region.
__global__ __launch_bounds__(256) void agg_kernel(const float* __restrict__ x,
                                                  const int* __restrict__ ei,
                                                  float* __restrict__ agg, int E) {
    long long idx = (long long)blockIdx.x * 256 + threadIdx.x;
    if (idx >= (long long)E * DD) return;
    int e = (int)(idx >> 7);
    int d = (int)(idx & (DD - 1));
    int s = ei[e];
    int t = ei[E + e];
    unsafeAtomicAdd(&agg[(size_t)t * DD + d], x[(size_t)s * DD + d]);
}

// ---------------- agg -> mean (in place) ----------------
__global__ __launch_bounds__(256) void mean_kernel(float* __restrict__ agg,
                                                   const float* __restrict__ deg, int n) {
    int idx = blockIdx.x * 256 + threadIdx.x;   // float4 index
    if (idx >= n * (DD / 4)) return;
    int row = idx >> 5;                          // 32 float4 per row
    float inv = 1.0f / fmaxf(deg[row], 1.0f);
    float4* p = (float4*)agg + idx;
    float4 v = *p;
    v.x *= inv; v.y *= inv; v.z *= inv; v.w *= inv;
    *p = v;
}

// ---------------- SAGE layer: out = relu(mean@Wl + b + x@Wr) ----------------
// grid.y = 4 column-quarters (32 cols each). Block 256 = 32 rows x 8 colgroups(x4).
// W quarters staged in LDS (32KB); row data streamed from global (L1-resident).
__global__ __launch_bounds__(256) void sage_layer_kernel(
    const float* __restrict__ mean, const float* __restrict__ x,
    const float* __restrict__ Wl, const float* __restrict__ Wr,
    const float* __restrict__ bias, float* __restrict__ out, int n) {
    __shared__ float sWl[DD][32];
    __shared__ float sWr[DD][32];
    const int tid = threadIdx.x;
    const int jh = blockIdx.y;               // 0..3
    for (int i = tid; i < DD * 32; i += 256) {
        int k = i >> 5, j = i & 31;
        sWl[k][j] = Wl[k * DD + jh * 32 + j];
        sWr[k][j] = Wr[k * DD + jh * 32 + j];
    }
    __syncthreads();
    const int cg = tid & 7;                  // 8 col groups * 4 cols = 32 cols
    const int rs = tid >> 3;                 // 32 rows per pass
    const int jbase = jh * 32 + cg * 4;
    const float4 bv = *(const float4*)(bias + jbase);
    const int row0 = blockIdx.x * 64;
    for (int rt = 0; rt < 64; rt += 32) {
        int row = row0 + rt + rs;
        int rowc = min(row, n - 1);
        const float* mrow = mean + (size_t)rowc * DD;
        const float* xrow = x + (size_t)rowc * DD;
        float a0 = bv.x, a1 = bv.y, a2 = bv.z, a3 = bv.w;
        #pragma unroll 4
        for (int k = 0; k < DD; k += 4) {
            float4 m4 = *(const float4*)(mrow + k);
            float4 x4 = *(const float4*)(xrow + k);
            #pragma unroll
            for (int kk = 0; kk < 4; ++kk) {
                float mv = ((const float*)&m4)[kk];
                float xv = ((const float*)&x4)[kk];
                float4 wl = *(const float4*)&sWl[k + kk][cg * 4];
                float4 wr = *(const float4*)&sWr[k + kk][cg * 4];
                a0 += mv * wl.x + xv * wr.x;
                a1 += mv * wl.y + xv * wr.y;
                a2 += mv * wl.z + xv * wr.z;
                a3 += mv * wl.w + xv * wr.w;
            }
        }
        a0 = fmaxf(a0, 0.f); a1 = fmaxf(a1, 0.f);
        a2 = fmaxf(a2, 0.f); a3 = fmaxf(a3, 0.f);
        if (row < n) {
            float4 o; o.x = a0; o.y = a1; o.z = a2; o.w = a3;
            *(float4*)(out + (size_t)row * DD + jbase) = o;
        }
    }
}

// ---------------- fused layer2 + output projection ----------------
// Each quarter-block computes a 32-col slice of h2 = relu(mean@W2l + b2 + h1@W2r),
// stages it in LDS, computes partial h2_slice @ Wout_slice, atomically adds to out.
__global__ __launch_bounds__(256) void sage_layer2_out_kernel(
    const float* __restrict__ mean, const float* __restrict__ x,
    const float* __restrict__ Wl, const float* __restrict__ Wr,
    const float* __restrict__ bias2, const float* __restrict__ Wout,
    float* __restrict__ out, int n) {
    __shared__ float sWl[DD][32];
    __shared__ float sWr[DD][32];
    __shared__ float sWo[32][CC];
    __shared__ __align__(16) float sH[32][36];
    const int tid = threadIdx.x;
    const int jh = blockIdx.y;               // 0..3
    for (int i = tid; i < DD * 32; i += 256) {
        int k = i >> 5, j = i & 31;
        sWl[k][j] = Wl[k * DD + jh * 32 + j];
        sWr[k][j] = Wr[k * DD + jh * 32 + j];
    }
    for (int i = tid; i < 32 * CC; i += 256) {
        int k = i >> 6, j = i & 63;
        sWo[k][j] = Wout[(jh * 32 + k) * CC + j];
    }
    __syncthreads();
    const int cg = tid & 7, rs = tid >> 3;
    const float4 bv = *(const float4*)(bias2 + jh * 32 + cg * 4);
    const int row0 = blockIdx.x * 64;
    for (int rt = 0; rt < 64; rt += 32) {
        int row = row0 + rt + rs;
        int rowc = min(row, n - 1);
        const float* mrow = mean + (size_t)rowc * DD;
        const float* xrow = x + (size_t)rowc * DD;
        float a0 = bv.x, a1 = bv.y, a2 = bv.z, a3 = bv.w;
        #pragma unroll 4
        for (int k = 0; k < DD; k += 4) {
            float4 m4 = *(const float4*)(mrow + k);
            float4 x4 = *(const float4*)(xrow + k);
            #pragma unroll
            for (int kk = 0; kk < 4; ++kk) {
                float mv = ((const float*)&m4)[kk];
                float xv = ((const float*)&x4)[kk];
                float4 wl = *(const float4*)&sWl[k + kk][cg * 4];
                float4 wr = *(const float4*)&sWr[k + kk][cg * 4];
                a0 += mv * wl.x + xv * wr.x;
                a1 += mv * wl.y + xv * wr.y;
                a2 += mv * wl.z + xv * wr.z;
                a3 += mv * wl.w + xv * wr.w;
            }
        }
        a0 = fmaxf(a0, 0.f); a1 = fmaxf(a1, 0.f);
        a2 = fmaxf(a2, 0.f); a3 = fmaxf(a3, 0.f);
        float4 hv4; hv4.x = a0; hv4.y = a1; hv4.z = a2; hv4.w = a3;
        *(float4*)&sH[rs][cg * 4] = hv4;
        __syncthreads();
        // phase 2: partial projection (this 32-slice of k) -> 64 out cols
        float p[8] = {0, 0, 0, 0, 0, 0, 0, 0};
        #pragma unroll 8
        for (int jj = 0; jj < 32; ++jj) {
            float hv = sH[rs][jj];
            float4 w0 = *(const float4*)&sWo[jj][cg * 8];
            float4 w1 = *(const float4*)&sWo[jj][cg * 8 + 4];
            p[0] += hv * w0.x; p[1] += hv * w0.y; p[2] += hv * w0.z; p[3] += hv * w0.w;
            p[4] += hv * w1.x; p[5] += hv * w1.y; p[6] += hv * w1.z; p[7] += hv * w1.w;
        }
        if (row < n) {
            float* op = out + (size_t)row * CC + cg * 8;
            #pragma unroll
            for (int c = 0; c < 8; ++c) unsafeAtomicAdd(op + c, p[c]);
        }
        __syncthreads();   // protect sH before next pass overwrites it
    }
}

// ---------------- + bout ----------------
__global__ __launch_bounds__(256) void bias_kernel(float* __restrict__ out,
                                                   const float* __restrict__ bout, int n) {
    int idx = blockIdx.x * 256 + threadIdx.x;   // float4 index over n*16
    if (idx >= n * (CC / 4)) return;
    int c4 = idx & 15;
    float4 b = *((const float4*)bout + c4);
    float4* p = (float4*)out + idx;
    float4 v = *p;
    v.x += b.x; v.y += b.y; v.z += b.z; v.w += b.w;
    *p = v;
}

extern "C" void kernel_launch(void* const* d_in, const int* in_sizes, int n_in,
                              void* d_out, int out_size, void* d_ws, size_t ws_size,
                              hipStream_t stream) {
    const float* x    = (const float*)d_in[0];
    const int*   ei   = (const int*)d_in[1];
    const float* W1l  = (const float*)d_in[2];
    const float* b1   = (const float*)d_in[3];
    const float* W1r  = (const float*)d_in[4];
    const float* W2l  = (const float*)d_in[5];
    const float* b2   = (const float*)d_in[6];
    const float* W2r  = (const float*)d_in[7];
    const float* Wout = (const float*)d_in[8];
    const float* bout = (const float*)d_in[9];
    float* out = (float*)d_out;
    const int n = in_sizes[0] / DD;       // 100000
    const int E = in_sizes[1] / 2;        // 1600000

    // workspace layout: deg (padded) | agg/mean (n*128) | h1 (n*128)  ~= 103 MB
    float* deg = (float*)d_ws;
    float* agg = deg + 100352;
    float* h1  = agg + (size_t)n * DD;

    hipMemsetAsync(deg, 0, sizeof(float) * (size_t)n, stream);
    hipMemsetAsync(agg, 0, sizeof(float) * (size_t)n * DD, stream);
    hipMemsetAsync(out, 0, sizeof(float) * (size_t)n * CC, stream);

    deg_kernel<<<(E + 255) / 256, 256, 0, stream>>>(ei, deg, E);
    agg_kernel<<<(int)(((long long)E * DD + 255) / 256), 256, 0, stream>>>(x, ei, agg, E);
    mean_kernel<<<(n * (DD / 4) + 255) / 256, 256, 0, stream>>>(agg, deg, n);

    dim3 lgrid((n + 63) / 64, 4);
    sage_layer_kernel<<<lgrid, 256, 0, stream>>>(agg, x, W1l, W1r, b1, h1, n);

    hipMemsetAsync(agg, 0, sizeof(float) * (size_t)n * DD, stream);
    agg_kernel<<<(int)(((long long)E * DD + 255) / 256), 256, 0, stream>>>(h1, ei, agg, E);
    mean_kernel<<<(n * (DD / 4) + 255) / 256, 256, 0, stream>>>(agg, deg, n);

    sage_layer2_out_kernel<<<lgrid, 256, 0, stream>>>(agg, h1, W2l, W2r, b2, Wout, out, n);
    bias_kernel<<<(n * (CC / 4) + 255) / 256, 256, 0, stream>>>(out, bout, n);
}

// Round 3
// 1925.759 us; speedup vs baseline: 1.2166x; 1.2166x over previous
//
#include <hip/hip_runtime.h>

#define DD 128
#define CC 64

// ---------------- degree count ----------------
__global__ __launch_bounds__(256) void deg_kernel(const int* __restrict__ ei,
                                                  float* __restrict__ deg, int E) {
    int e = blockIdx.x * 256 + threadIdx.x;
    if (e < E) unsafeAtomicAdd(&deg[ei[E + e]], 1.0f);
}

// ---------------- scatter-add aggregation ----------------
// thread -> (edge, dim): wave covers 64 consecutive dims of one edge
// => wave-uniform edge-index loads, coalesced gather + atomic region.
__global__ __launch_bounds__(256) void agg_kernel(const float* __restrict__ x,
                                                  const int* __restrict__ ei,
                                                  float* __restrict__ agg, int E) {
    long long idx = (long long)blockIdx.x * 256 + threadIdx.x;
    if (idx >= (long long)E * DD) return;
    int e = (int)(idx >> 7);
    int d = (int)(idx & (DD - 1));
    int s = ei[e];
    int t = ei[E + e];
    unsafeAtomicAdd(&agg[(size_t)t * DD + d], x[(size_t)s * DD + d]);
}

// ---------------- SAGE layer: out = relu((agg/deg)@Wl + b + x@Wr) ----------------
// One block = 64 rows x ALL 128 cols (rows read once). Thread = 8 rows x 4 cols.
// Weights streamed through LDS in 32-k slices. deg division fused at load.
// NOTE: `out` may alias `agg` (layer 2 writes in place): each block reads only
// its own 64 rows and stores only after all its reads -> safe; no restrict here.
__global__ __launch_bounds__(256) void layer_kernel(
    const float* agg, const float* __restrict__ deg,
    const float* __restrict__ x,
    const float* __restrict__ Wl, const float* __restrict__ Wr,
    const float* __restrict__ bias, float* out, int n) {
    __shared__ float sWl[32][DD];
    __shared__ float sWr[32][DD];
    const int tid = threadIdx.x;
    const int rg = tid >> 5;          // 0..7
    const int cg = tid & 31;          // 0..31
    const int c0 = cg * 4;
    const int row0 = blockIdx.x * 64 + rg * 8;

    float inv[8];
    const float* aggp[8];
    const float* xp[8];
    #pragma unroll
    for (int r = 0; r < 8; ++r) {
        int rowc = min(row0 + r, n - 1);
        inv[r] = 1.0f / fmaxf(deg[rowc], 1.0f);
        aggp[r] = agg + (size_t)rowc * DD;
        xp[r]   = x   + (size_t)rowc * DD;
    }
    const float4 bv = *(const float4*)(bias + c0);
    float acc[8][4];
    #pragma unroll
    for (int r = 0; r < 8; ++r) {
        acc[r][0] = bv.x; acc[r][1] = bv.y; acc[r][2] = bv.z; acc[r][3] = bv.w;
    }

    for (int ks = 0; ks < 4; ++ks) {
        __syncthreads();
        for (int i = tid; i < 1024; i += 256) {
            ((float4*)sWl)[i] = ((const float4*)(Wl + ks * 32 * DD))[i];
            ((float4*)sWr)[i] = ((const float4*)(Wr + ks * 32 * DD))[i];
        }
        __syncthreads();
        const int k0 = ks * 32;
        for (int kk = 0; kk < 32; kk += 4) {
            float4 a4[8], x4[8];
            #pragma unroll
            for (int r = 0; r < 8; ++r) {
                a4[r] = *(const float4*)(aggp[r] + k0 + kk);
                x4[r] = *(const float4*)(xp[r] + k0 + kk);
            }
            #pragma unroll
            for (int j = 0; j < 4; ++j) {
                float4 wl = *(const float4*)&sWl[kk + j][c0];
                float4 wr = *(const float4*)&sWr[kk + j][c0];
                #pragma unroll
                for (int r = 0; r < 8; ++r) {
                    float mv = ((const float*)&a4[r])[j] * inv[r];
                    float xv = ((const float*)&x4[r])[j];
                    acc[r][0] += mv * wl.x + xv * wr.x;
                    acc[r][1] += mv * wl.y + xv * wr.y;
                    acc[r][2] += mv * wl.z + xv * wr.z;
                    acc[r][3] += mv * wl.w + xv * wr.w;
                }
            }
        }
    }
    #pragma unroll
    for (int r = 0; r < 8; ++r) {
        int row = row0 + r;
        if (row < n) {
            float4 o;
            o.x = fmaxf(acc[r][0], 0.f);
            o.y = fmaxf(acc[r][1], 0.f);
            o.z = fmaxf(acc[r][2], 0.f);
            o.w = fmaxf(acc[r][3], 0.f);
            *(float4*)(out + (size_t)row * DD + c0) = o;
        }
    }
}

// ---------------- output projection: out = h2 @ Wout + bout ----------------
// Block = 64 rows; 4 threads/row x 16 cols. Wout staged whole in LDS (32 KB).
__global__ __launch_bounds__(256) void proj_kernel(
    const float* __restrict__ h2, const float* __restrict__ Wout,
    const float* __restrict__ bout, float* __restrict__ out, int n) {
    __shared__ float sWo[DD][CC];
    const int tid = threadIdx.x;
    for (int i = tid; i < DD * CC / 4; i += 256) {
        ((float4*)sWo)[i] = ((const float4*)Wout)[i];
    }
    __syncthreads();
    const int prow = tid >> 2;        // 0..63
    const int oc = (tid & 3) * 16;    // 0,16,32,48
    const int row = blockIdx.x * 64 + prow;
    const int rowc = min(row, n - 1);
    const float* hrow = h2 + (size_t)rowc * DD;
    float po[16];
    #pragma unroll
    for (int q = 0; q < 4; ++q) {
        float4 b4 = *(const float4*)(bout + oc + q * 4);
        po[q * 4 + 0] = b4.x; po[q * 4 + 1] = b4.y;
        po[q * 4 + 2] = b4.z; po[q * 4 + 3] = b4.w;
    }
    for (int k = 0; k < DD; k += 4) {
        float4 h4 = *(const float4*)(hrow + k);
        #pragma unroll
        for (int j = 0; j < 4; ++j) {
            float hv = ((const float*)&h4)[j];
            const float* wrow = &sWo[k + j][oc];
            #pragma unroll
            for (int q = 0; q < 4; ++q) {
                float4 w4 = *(const float4*)(wrow + q * 4);
                po[q * 4 + 0] += hv * w4.x;
                po[q * 4 + 1] += hv * w4.y;
                po[q * 4 + 2] += hv * w4.z;
                po[q * 4 + 3] += hv * w4.w;
            }
        }
    }
    if (row < n) {
        #pragma unroll
        for (int q = 0; q < 4; ++q) {
            float4 o;
            o.x = po[q * 4 + 0]; o.y = po[q * 4 + 1];
            o.z = po[q * 4 + 2]; o.w = po[q * 4 + 3];
            *(float4*)(out + (size_t)row * CC + oc + q * 4) = o;
        }
    }
}

extern "C" void kernel_launch(void* const* d_in, const int* in_sizes, int n_in,
                              void* d_out, int out_size, void* d_ws, size_t ws_size,
                              hipStream_t stream) {
    const float* x    = (const float*)d_in[0];
    const int*   ei   = (const int*)d_in[1];
    const float* W1l  = (const float*)d_in[2];
    const float* b1   = (const float*)d_in[3];
    const float* W1r  = (const float*)d_in[4];
    const float* W2l  = (const float*)d_in[5];
    const float* b2   = (const float*)d_in[6];
    const float* W2r  = (const float*)d_in[7];
    const float* Wout = (const float*)d_in[8];
    const float* bout = (const float*)d_in[9];
    float* out = (float*)d_out;
    const int n = in_sizes[0] / DD;       // 100000
    const int E = in_sizes[1] / 2;        // 1600000

    // workspace: deg (padded) | agg (n*128) | h1 (n*128)  ~= 103 MB
    float* deg = (float*)d_ws;
    float* agg = deg + 100352;
    float* h1  = agg + (size_t)n * DD;

    hipMemsetAsync(deg, 0, sizeof(float) * (size_t)n, stream);
    hipMemsetAsync(agg, 0, sizeof(float) * (size_t)n * DD, stream);

    deg_kernel<<<(E + 255) / 256, 256, 0, stream>>>(ei, deg, E);
    agg_kernel<<<(int)(((long long)E * DD + 255) / 256), 256, 0, stream>>>(x, ei, agg, E);

    const int nblk = (n + 63) / 64;
    layer_kernel<<<nblk, 256, 0, stream>>>(agg, deg, x, W1l, W1r, b1, h1, n);

    hipMemsetAsync(agg, 0, sizeof(float) * (size_t)n * DD, stream);
    agg_kernel<<<(int)(((long long)E * DD + 255) / 256), 256, 0, stream>>>(h1, ei, agg, E);

    // layer 2 writes h2 in place into agg (per-block row ownership makes this safe)
    layer_kernel<<<nblk, 256, 0, stream>>>(agg, deg, h1, W2l, W2r, b2, agg, n);

    proj_kernel<<<nblk, 256, 0, stream>>>(agg, Wout, bout, out, n);
}

// Round 4
// 905.068 us; speedup vs baseline: 2.5886x; 2.1277x over previous
//
#include <hip/hip_runtime.h>

#define DD 128
#define CC 64

// ================= CSR build =================
__global__ __launch_bounds__(256) void cnt_kernel(const int* __restrict__ ei,
                                                  int* __restrict__ cnt, int E) {
    int e = blockIdx.x * 256 + threadIdx.x;
    if (e < E) atomicAdd(&cnt[ei[E + e]], 1);
}

// block scans 2048 elements (256 thr x 8); writes per-element exclusive
// prefix (within block) and the block total.
__global__ __launch_bounds__(256) void scan1_kernel(const int* __restrict__ cnt,
                                                    int* __restrict__ offs,
                                                    int* __restrict__ bsum, int n) {
    __shared__ int s[256];
    const int t = threadIdx.x;
    const int base = blockIdx.x * 2048 + t * 8;
    int v[8];
    int sum = 0;
    #pragma unroll
    for (int j = 0; j < 8; ++j) {
        int idx = base + j;
        v[j] = (idx < n) ? cnt[idx] : 0;
        sum += v[j];
    }
    s[t] = sum;
    __syncthreads();
    for (int off = 1; off < 256; off <<= 1) {
        int xv = 0;
        if (t >= off) xv = s[t - off];
        __syncthreads();
        if (t >= off) s[t] += xv;
        __syncthreads();
    }
    int run = s[t] - sum;    // exclusive base for this thread
    #pragma unroll
    for (int j = 0; j < 8; ++j) {
        int idx = base + j;
        if (idx < n) offs[idx] = run;
        run += v[j];
    }
    if (t == 255) bsum[blockIdx.x] = s[255];
}

__global__ void scan2_kernel(const int* __restrict__ bsum,
                             int* __restrict__ bscan, int nb) {
    if (threadIdx.x == 0 && blockIdx.x == 0) {
        int acc = 0;
        for (int i = 0; i < nb; ++i) { bscan[i] = acc; acc += bsum[i]; }
    }
}

__global__ __launch_bounds__(256) void scan_fix_kernel(int* __restrict__ offs,
                                                       int* __restrict__ cursor,
                                                       const int* __restrict__ bscan,
                                                       int n) {
    int i = blockIdx.x * 256 + threadIdx.x;
    if (i < n) {
        int v = offs[i] + bscan[i >> 11];
        offs[i] = v;
        cursor[i] = v;
    }
}

__global__ __launch_bounds__(256) void scatter_kernel(const int* __restrict__ ei,
                                                      int* __restrict__ cursor,
                                                      int* __restrict__ csr, int E) {
    int e = blockIdx.x * 256 + threadIdx.x;
    if (e < E) {
        int d = ei[E + e];
        int p = atomicAdd(&cursor[d], 1);
        csr[p] = ei[e];
    }
}

// ================= CSR gather-aggregate: mean over neighbors =================
// One wave per node; lane covers 2 dims (float2). Neighbor rows gathered from
// L2/L3, accumulated in registers, mean written exactly once. No atomics.
__global__ __launch_bounds__(256) void csr_agg_kernel(
    const float* __restrict__ x, const int* __restrict__ offs,
    const int* __restrict__ cnt, const int* __restrict__ csr,
    float* __restrict__ mean, int n) {
    int node = blockIdx.x * 4 + (threadIdx.x >> 6);
    if (node >= n) return;
    const int lane = threadIdx.x & 63;
    const int start = offs[node];
    const int c = cnt[node];
    float ax = 0.f, ay = 0.f;
    int j = 0;
    for (; j + 4 <= c; j += 4) {
        int s0 = csr[start + j];
        int s1 = csr[start + j + 1];
        int s2 = csr[start + j + 2];
        int s3 = csr[start + j + 3];
        float2 v0 = *(const float2*)(x + (size_t)s0 * DD + 2 * lane);
        float2 v1 = *(const float2*)(x + (size_t)s1 * DD + 2 * lane);
        float2 v2 = *(const float2*)(x + (size_t)s2 * DD + 2 * lane);
        float2 v3 = *(const float2*)(x + (size_t)s3 * DD + 2 * lane);
        ax += v0.x + v1.x + v2.x + v3.x;
        ay += v0.y + v1.y + v2.y + v3.y;
    }
    for (; j < c; ++j) {
        int s = csr[start + j];
        float2 v = *(const float2*)(x + (size_t)s * DD + 2 * lane);
        ax += v.x; ay += v.y;
    }
    float inv = 1.0f / fmaxf((float)c, 1.0f);
    float2 o; o.x = ax * inv; o.y = ay * inv;
    *(float2*)(mean + (size_t)node * DD + 2 * lane) = o;
}

// ================= SAGE layer: out = relu(mean@Wl + b + x@Wr) =================
// One block = 64 rows x ALL 128 cols (rows read once). Thread = 8 rows x 4 cols.
// Weights streamed through LDS in 32-k slices.
// NOTE: `out` may alias `mean` (layer 2 in place): each block reads only its
// own 64 rows and stores after all its reads -> safe; no restrict on that pair.
__global__ __launch_bounds__(256) void layer_kernel(
    const float* mean, const float* __restrict__ x,
    const float* __restrict__ Wl, const float* __restrict__ Wr,
    const float* __restrict__ bias, float* out, int n) {
    __shared__ float sWl[32][DD];
    __shared__ float sWr[32][DD];
    const int tid = threadIdx.x;
    const int rg = tid >> 5;          // 0..7
    const int cg = tid & 31;          // 0..31
    const int c0 = cg * 4;
    const int row0 = blockIdx.x * 64 + rg * 8;

    const float* mp[8];
    const float* xp[8];
    #pragma unroll
    for (int r = 0; r < 8; ++r) {
        int rowc = min(row0 + r, n - 1);
        mp[r] = mean + (size_t)rowc * DD;
        xp[r] = x    + (size_t)rowc * DD;
    }
    const float4 bv = *(const float4*)(bias + c0);
    float acc[8][4];
    #pragma unroll
    for (int r = 0; r < 8; ++r) {
        acc[r][0] = bv.x; acc[r][1] = bv.y; acc[r][2] = bv.z; acc[r][3] = bv.w;
    }

    for (int ks = 0; ks < 4; ++ks) {
        __syncthreads();
        for (int i = tid; i < 1024; i += 256) {
            ((float4*)sWl)[i] = ((const float4*)(Wl + ks * 32 * DD))[i];
            ((float4*)sWr)[i] = ((const float4*)(Wr + ks * 32 * DD))[i];
        }
        __syncthreads();
        const int k0 = ks * 32;
        for (int kk = 0; kk < 32; kk += 4) {
            float4 m4[8], x4[8];
            #pragma unroll
            for (int r = 0; r < 8; ++r) {
                m4[r] = *(const float4*)(mp[r] + k0 + kk);
                x4[r] = *(const float4*)(xp[r] + k0 + kk);
            }
            #pragma unroll
            for (int j = 0; j < 4; ++j) {
                float4 wl = *(const float4*)&sWl[kk + j][c0];
                float4 wr = *(const float4*)&sWr[kk + j][c0];
                #pragma unroll
                for (int r = 0; r < 8; ++r) {
                    float mv = ((const float*)&m4[r])[j];
                    float xv = ((const float*)&x4[r])[j];
                    acc[r][0] += mv * wl.x + xv * wr.x;
                    acc[r][1] += mv * wl.y + xv * wr.y;
                    acc[r][2] += mv * wl.z + xv * wr.z;
                    acc[r][3] += mv * wl.w + xv * wr.w;
                }
            }
        }
    }
    #pragma unroll
    for (int r = 0; r < 8; ++r) {
        int row = row0 + r;
        if (row < n) {
            float4 o;
            o.x = fmaxf(acc[r][0], 0.f);
            o.y = fmaxf(acc[r][1], 0.f);
            o.z = fmaxf(acc[r][2], 0.f);
            o.w = fmaxf(acc[r][3], 0.f);
            *(float4*)(out + (size_t)row * DD + c0) = o;
        }
    }
}

// ================= output projection: out = h2 @ Wout + bout =================
__global__ __launch_bounds__(256) void proj_kernel(
    const float* __restrict__ h2, const float* __restrict__ Wout,
    const float* __restrict__ bout, float* __restrict__ out, int n) {
    __shared__ float sWo[DD][CC];
    const int tid = threadIdx.x;
    for (int i = tid; i < DD * CC / 4; i += 256) {
        ((float4*)sWo)[i] = ((const float4*)Wout)[i];
    }
    __syncthreads();
    const int prow = tid >> 2;        // 0..63
    const int oc = (tid & 3) * 16;    // 0,16,32,48
    const int row = blockIdx.x * 64 + prow;
    const int rowc = min(row, n - 1);
    const float* hrow = h2 + (size_t)rowc * DD;
    float po[16];
    #pragma unroll
    for (int q = 0; q < 4; ++q) {
        float4 b4 = *(const float4*)(bout + oc + q * 4);
        po[q * 4 + 0] = b4.x; po[q * 4 + 1] = b4.y;
        po[q * 4 + 2] = b4.z; po[q * 4 + 3] = b4.w;
    }
    for (int k = 0; k < DD; k += 4) {
        float4 h4 = *(const float4*)(hrow + k);
        #pragma unroll
        for (int j = 0; j < 4; ++j) {
            float hv = ((const float*)&h4)[j];
            const float* wrow = &sWo[k + j][oc];
            #pragma unroll
            for (int q = 0; q < 4; ++q) {
                float4 w4 = *(const float4*)(wrow + q * 4);
                po[q * 4 + 0] += hv * w4.x;
                po[q * 4 + 1] += hv * w4.y;
                po[q * 4 + 2] += hv * w4.z;
                po[q * 4 + 3] += hv * w4.w;
            }
        }
    }
    if (row < n) {
        #pragma unroll
        for (int q = 0; q < 4; ++q) {
            float4 o;
            o.x = po[q * 4 + 0]; o.y = po[q * 4 + 1];
            o.z = po[q * 4 + 2]; o.w = po[q * 4 + 3];
            *(float4*)(out + (size_t)row * CC + oc + q * 4) = o;
        }
    }
}

extern "C" void kernel_launch(void* const* d_in, const int* in_sizes, int n_in,
                              void* d_out, int out_size, void* d_ws, size_t ws_size,
                              hipStream_t stream) {
    const float* x    = (const float*)d_in[0];
    const int*   ei   = (const int*)d_in[1];
    const float* W1l  = (const float*)d_in[2];
    const float* b1   = (const float*)d_in[3];
    const float* W1r  = (const float*)d_in[4];
    const float* W2l  = (const float*)d_in[5];
    const float* b2   = (const float*)d_in[6];
    const float* W2r  = (const float*)d_in[7];
    const float* Wout = (const float*)d_in[8];
    const float* bout = (const float*)d_in[9];
    float* out = (float*)d_out;
    const int n = in_sizes[0] / DD;       // 100000
    const int E = in_sizes[1] / 2;        // 1600000

    const int NB_SCAN = (n + 2047) / 2048;

    // workspace layout (ints then floats), ~110 MB total
    int* cnt    = (int*)d_ws;             // n
    int* offs   = cnt + 100352;           // n
    int* cursor = offs + 100352;          // n
    int* bsum   = cursor + 100352;        // NB_SCAN
    int* bscan  = bsum + 256;             // NB_SCAN
    int* csr    = bscan + 256;            // E
    float* agg  = (float*)(csr + ((E + 255) & ~255));   // n*128
    float* h1   = agg + (size_t)n * DD;                 // n*128

    hipMemsetAsync(cnt, 0, sizeof(int) * (size_t)n, stream);
    cnt_kernel<<<(E + 255) / 256, 256, 0, stream>>>(ei, cnt, E);
    scan1_kernel<<<NB_SCAN, 256, 0, stream>>>(cnt, offs, bsum, n);
    scan2_kernel<<<1, 64, 0, stream>>>(bsum, bscan, NB_SCAN);
    scan_fix_kernel<<<(n + 255) / 256, 256, 0, stream>>>(offs, cursor, bscan, n);
    scatter_kernel<<<(E + 255) / 256, 256, 0, stream>>>(ei, cursor, csr, E);

    const int nblk = (n + 63) / 64;
    const int ablk = (n + 3) / 4;

    csr_agg_kernel<<<ablk, 256, 0, stream>>>(x, offs, cnt, csr, agg, n);
    layer_kernel<<<nblk, 256, 0, stream>>>(agg, x, W1l, W1r, b1, h1, n);

    csr_agg_kernel<<<ablk, 256, 0, stream>>>(h1, offs, cnt, csr, agg, n);
    // layer 2 writes h2 in place into agg (per-block row ownership -> safe)
    layer_kernel<<<nblk, 256, 0, stream>>>(agg, h1, W2l, W2r, b2, agg, n);

    proj_kernel<<<nblk, 256, 0, stream>>>(agg, Wout, bout, out, n);
}

// Round 5
// 555.937 us; speedup vs baseline: 4.2143x; 1.6280x over previous
//
#include <hip/hip_runtime.h>

#define DD 128
#define CC 64

typedef __attribute__((ext_vector_type(8))) short short8v;
typedef __attribute__((ext_vector_type(4))) float f32x4;

static __device__ inline ushort f2bf_rne(float f) {
    unsigned u = __float_as_uint(f);
    unsigned r = (u + 0x7FFFu + ((u >> 16) & 1u)) >> 16;
    return (ushort)r;
}
static __device__ inline float bf2f(ushort h) {
    return __uint_as_float(((unsigned)h) << 16);
}

// ================= CSR build =================
__global__ __launch_bounds__(256) void cnt_kernel(const int* __restrict__ ei,
                                                  int* __restrict__ cnt, int E) {
    int e = blockIdx.x * 256 + threadIdx.x;
    if (e < E) atomicAdd(&cnt[ei[E + e]], 1);
}

__global__ __launch_bounds__(256) void scan1_kernel(const int* __restrict__ cnt,
                                                    int* __restrict__ offs,
                                                    int* __restrict__ bsum, int n) {
    __shared__ int s[256];
    const int t = threadIdx.x;
    const int base = blockIdx.x * 2048 + t * 8;
    int v[8];
    int sum = 0;
    #pragma unroll
    for (int j = 0; j < 8; ++j) {
        int idx = base + j;
        v[j] = (idx < n) ? cnt[idx] : 0;
        sum += v[j];
    }
    s[t] = sum;
    __syncthreads();
    for (int off = 1; off < 256; off <<= 1) {
        int xv = 0;
        if (t >= off) xv = s[t - off];
        __syncthreads();
        if (t >= off) s[t] += xv;
        __syncthreads();
    }
    int run = s[t] - sum;
    #pragma unroll
    for (int j = 0; j < 8; ++j) {
        int idx = base + j;
        if (idx < n) offs[idx] = run;
        run += v[j];
    }
    if (t == 255) bsum[blockIdx.x] = s[255];
}

__global__ void scan2_kernel(const int* __restrict__ bsum,
                             int* __restrict__ bscan, int nb) {
    if (threadIdx.x == 0 && blockIdx.x == 0) {
        int acc = 0;
        for (int i = 0; i < nb; ++i) { bscan[i] = acc; acc += bsum[i]; }
    }
}

__global__ __launch_bounds__(256) void scan_fix_kernel(int* __restrict__ offs,
                                                       int* __restrict__ cursor,
                                                       const int* __restrict__ bscan,
                                                       int n) {
    int i = blockIdx.x * 256 + threadIdx.x;
    if (i < n) {
        int v = offs[i] + bscan[i >> 11];
        offs[i] = v;
        cursor[i] = v;
    }
}

__global__ __launch_bounds__(256) void scatter_kernel(const int* __restrict__ ei,
                                                      int* __restrict__ cursor,
                                                      int* __restrict__ csr, int E) {
    int e = blockIdx.x * 256 + threadIdx.x;
    if (e < E) {
        int d = ei[E + e];
        int p = atomicAdd(&cursor[d], 1);
        csr[p] = ei[e];
    }
}

// ================= CSR gather-aggregate: mean over neighbors =================
__global__ __launch_bounds__(256) void csr_agg_kernel(
    const float* __restrict__ x, const int* __restrict__ offs,
    const int* __restrict__ cnt, const int* __restrict__ csr,
    float* __restrict__ mean, int n) {
    int node = blockIdx.x * 4 + (threadIdx.x >> 6);
    if (node >= n) return;
    const int lane = threadIdx.x & 63;
    const int start = offs[node];
    const int c = cnt[node];
    float ax = 0.f, ay = 0.f;
    int j = 0;
    for (; j + 4 <= c; j += 4) {
        int s0 = csr[start + j];
        int s1 = csr[start + j + 1];
        int s2 = csr[start + j + 2];
        int s3 = csr[start + j + 3];
        float2 v0 = *(const float2*)(x + (size_t)s0 * DD + 2 * lane);
        float2 v1 = *(const float2*)(x + (size_t)s1 * DD + 2 * lane);
        float2 v2 = *(const float2*)(x + (size_t)s2 * DD + 2 * lane);
        float2 v3 = *(const float2*)(x + (size_t)s3 * DD + 2 * lane);
        ax += v0.x + v1.x + v2.x + v3.x;
        ay += v0.y + v1.y + v2.y + v3.y;
    }
    for (; j < c; ++j) {
        int s = csr[start + j];
        float2 v = *(const float2*)(x + (size_t)s * DD + 2 * lane);
        ax += v.x; ay += v.y;
    }
    float inv = 1.0f / fmaxf((float)c, 1.0f);
    float2 o; o.x = ax * inv; o.y = ay * inv;
    *(float2*)(mean + (size_t)node * DD + 2 * lane) = o;
}

// ====== weight prep: WT_hi/lo[c][k] (k: 0..127 = Wl, 128..255 = Wr), bf16 split ======
__global__ __launch_bounds__(256) void wsplit_kernel(
    const float* __restrict__ Wl, const float* __restrict__ Wr,
    ushort* __restrict__ WT_hi, ushort* __restrict__ WT_lo) {
    int idx = blockIdx.x * 256 + threadIdx.x;   // c*256 + k
    if (idx >= DD * 256) return;
    int c = idx >> 8, k = idx & 255;
    float v = (k < DD) ? Wl[k * DD + c] : Wr[(k - DD) * DD + c];
    ushort h = f2bf_rne(v);
    ushort lo = f2bf_rne(v - bf2f(h));
    WT_hi[idx] = h;
    WT_lo[idx] = lo;
}

// ================= MFMA SAGE layer =================
// out = relu([mean | xr] @ WT^T + bias), WT = [128 cols][256 k] bf16 hi/lo.
// Block: 64 rows x 128 cols, K=256 in 8 slices of 32. 4 waves: wave w owns
// rows w*16..+15, all 8 col-tiles. hi/lo split => ~f32 precision:
// acc += a_hi*b_hi + a_lo*b_hi + a_hi*b_lo.
// A/B frag staging uses identical per-lane k-packing (8 consecutive k per
// lane-group) -> correct product for any internal MFMA k-decode; only the
// C/D mapping (col=lane&15, row=4*(lane>>4)+reg, HW-verified) must be exact.
// NOTE: `out` may alias `mean` (layer 2 in place): blocks read only their own
// 64 rows during the K loop and store only in the epilogue -> safe.
__global__ __launch_bounds__(256) void layer_mfma_kernel(
    const float* mean, const float* xr,
    const ushort* __restrict__ WT_hi, const ushort* __restrict__ WT_lo,
    const float* __restrict__ bias, float* out, int n) {
    __shared__ ushort sAh[64][40], sAl[64][40];     // padded stride 80B
    __shared__ ushort sBh[128][40], sBl[128][40];
    const int tid = threadIdx.x;
    const int w = tid >> 6;
    const int l = tid & 63;
    const int row0 = blockIdx.x * 64;

    // staging roles
    const int ar  = tid >> 2;            // A row 0..63
    const int akq = (tid & 3) * 8;       // A k offset within slice
    const int arowg = min(row0 + ar, n - 1);
    const int bc  = tid >> 1;            // B col 0..127
    const int bkh = (tid & 1) * 16;      // B k offset within slice

    // frag roles
    const int arow = w * 16 + (l & 15);
    const int kb   = (l >> 4) * 8;
    const int lcol = l & 15;

    f32x4 acc[8];
    #pragma unroll
    for (int t = 0; t < 8; ++t) acc[t] = (f32x4){0.f, 0.f, 0.f, 0.f};

    for (int s = 0; s < 8; ++s) {
        const int k0 = s * 32;
        const float* Asrc = (k0 < DD) ? (mean + (size_t)arowg * DD + k0)
                                      : (xr + (size_t)arowg * DD + (k0 - DD));
        float4 v0 = *(const float4*)(Asrc + akq);
        float4 v1 = *(const float4*)(Asrc + akq + 4);
        float vv[8] = {v0.x, v0.y, v0.z, v0.w, v1.x, v1.y, v1.z, v1.w};
        short8v ah_w, al_w;
        #pragma unroll
        for (int j = 0; j < 8; ++j) {
            ushort h = f2bf_rne(vv[j]);
            ah_w[j] = (short)h;
            al_w[j] = (short)f2bf_rne(vv[j] - bf2f(h));
        }
        const ushort* bhp = WT_hi + bc * 256 + k0 + bkh;
        const ushort* blp = WT_lo + bc * 256 + k0 + bkh;
        short8v bh0 = *(const short8v*)bhp;
        short8v bh1 = *(const short8v*)(bhp + 8);
        short8v bl0 = *(const short8v*)blp;
        short8v bl1 = *(const short8v*)(blp + 8);

        __syncthreads();   // previous slice's frag reads complete
        *(short8v*)&sAh[ar][akq] = ah_w;
        *(short8v*)&sAl[ar][akq] = al_w;
        *(short8v*)&sBh[bc][bkh]     = bh0;
        *(short8v*)&sBh[bc][bkh + 8] = bh1;
        *(short8v*)&sBl[bc][bkh]     = bl0;
        *(short8v*)&sBl[bc][bkh + 8] = bl1;
        __syncthreads();

        short8v ah = *(const short8v*)&sAh[arow][kb];
        short8v al = *(const short8v*)&sAl[arow][kb];
        #pragma unroll
        for (int t = 0; t < 8; ++t) {
            short8v bh = *(const short8v*)&sBh[t * 16 + lcol][kb];
            short8v bl = *(const short8v*)&sBl[t * 16 + lcol][kb];
            acc[t] = __builtin_amdgcn_mfma_f32_16x16x32_bf16(ah, bh, acc[t], 0, 0, 0);
            acc[t] = __builtin_amdgcn_mfma_f32_16x16x32_bf16(al, bh, acc[t], 0, 0, 0);
            acc[t] = __builtin_amdgcn_mfma_f32_16x16x32_bf16(ah, bl, acc[t], 0, 0, 0);
        }
    }

    // epilogue: C/D layout col=lane&15, row=4*(lane>>4)+reg
    const int orow0 = row0 + w * 16 + (l >> 4) * 4;
    #pragma unroll
    for (int t = 0; t < 8; ++t) {
        const int col = t * 16 + lcol;
        const float b = bias[col];
        #pragma unroll
        for (int r = 0; r < 4; ++r) {
            int row = orow0 + r;
            if (row < n) out[(size_t)row * DD + col] = fmaxf(acc[t][r] + b, 0.f);
        }
    }
}

// ================= output projection: out = h2 @ Wout + bout =================
__global__ __launch_bounds__(256) void proj_kernel(
    const float* __restrict__ h2, const float* __restrict__ Wout,
    const float* __restrict__ bout, float* __restrict__ out, int n) {
    __shared__ float sWo[DD][CC];
    const int tid = threadIdx.x;
    for (int i = tid; i < DD * CC / 4; i += 256) {
        ((float4*)sWo)[i] = ((const float4*)Wout)[i];
    }
    __syncthreads();
    const int prow = tid >> 2;
    const int oc = (tid & 3) * 16;
    const int row = blockIdx.x * 64 + prow;
    const int rowc = min(row, n - 1);
    const float* hrow = h2 + (size_t)rowc * DD;
    float po[16];
    #pragma unroll
    for (int q = 0; q < 4; ++q) {
        float4 b4 = *(const float4*)(bout + oc + q * 4);
        po[q * 4 + 0] = b4.x; po[q * 4 + 1] = b4.y;
        po[q * 4 + 2] = b4.z; po[q * 4 + 3] = b4.w;
    }
    for (int k = 0; k < DD; k += 4) {
        float4 h4 = *(const float4*)(hrow + k);
        #pragma unroll
        for (int j = 0; j < 4; ++j) {
            float hv = ((const float*)&h4)[j];
            const float* wrow = &sWo[k + j][oc];
            #pragma unroll
            for (int q = 0; q < 4; ++q) {
                float4 w4 = *(const float4*)(wrow + q * 4);
                po[q * 4 + 0] += hv * w4.x;
                po[q * 4 + 1] += hv * w4.y;
                po[q * 4 + 2] += hv * w4.z;
                po[q * 4 + 3] += hv * w4.w;
            }
        }
    }
    if (row < n) {
        #pragma unroll
        for (int q = 0; q < 4; ++q) {
            float4 o;
            o.x = po[q * 4 + 0]; o.y = po[q * 4 + 1];
            o.z = po[q * 4 + 2]; o.w = po[q * 4 + 3];
            *(float4*)(out + (size_t)row * CC + oc + q * 4) = o;
        }
    }
}

extern "C" void kernel_launch(void* const* d_in, const int* in_sizes, int n_in,
                              void* d_out, int out_size, void* d_ws, size_t ws_size,
                              hipStream_t stream) {
    const float* x    = (const float*)d_in[0];
    const int*   ei   = (const int*)d_in[1];
    const float* W1l  = (const float*)d_in[2];
    const float* b1   = (const float*)d_in[3];
    const float* W1r  = (const float*)d_in[4];
    const float* W2l  = (const float*)d_in[5];
    const float* b2   = (const float*)d_in[6];
    const float* W2r  = (const float*)d_in[7];
    const float* Wout = (const float*)d_in[8];
    const float* bout = (const float*)d_in[9];
    float* out = (float*)d_out;
    const int n = in_sizes[0] / DD;       // 100000
    const int E = in_sizes[1] / 2;        // 1600000

    const int NB_SCAN = (n + 2047) / 2048;

    // workspace layout
    int* cnt    = (int*)d_ws;                           // n
    int* offs   = cnt + 100352;                         // n
    int* cursor = offs + 100352;                        // n
    int* bsum   = cursor + 100352;                      // NB_SCAN
    int* bscan  = bsum + 256;                           // NB_SCAN
    int* csr    = bscan + 256;                          // E
    float* agg  = (float*)(csr + ((E + 255) & ~255));   // n*128
    float* h1   = agg + (size_t)n * DD;                 // n*128
    ushort* WT1h = (ushort*)(h1 + (size_t)n * DD);      // 128*256 each
    ushort* WT1l = WT1h + DD * 256;
    ushort* WT2h = WT1l + DD * 256;
    ushort* WT2l = WT2h + DD * 256;

    hipMemsetAsync(cnt, 0, sizeof(int) * (size_t)n, stream);
    cnt_kernel<<<(E + 255) / 256, 256, 0, stream>>>(ei, cnt, E);
    scan1_kernel<<<NB_SCAN, 256, 0, stream>>>(cnt, offs, bsum, n);
    scan2_kernel<<<1, 64, 0, stream>>>(bsum, bscan, NB_SCAN);
    scan_fix_kernel<<<(n + 255) / 256, 256, 0, stream>>>(offs, cursor, bscan, n);
    scatter_kernel<<<(E + 255) / 256, 256, 0, stream>>>(ei, cursor, csr, E);

    wsplit_kernel<<<DD, 256, 0, stream>>>(W1l, W1r, WT1h, WT1l);
    wsplit_kernel<<<DD, 256, 0, stream>>>(W2l, W2r, WT2h, WT2l);

    const int nblk = (n + 63) / 64;
    const int ablk = (n + 3) / 4;

    csr_agg_kernel<<<ablk, 256, 0, stream>>>(x, offs, cnt, csr, agg, n);
    layer_mfma_kernel<<<nblk, 256, 0, stream>>>(agg, x, WT1h, WT1l, b1, h1, n);

    csr_agg_kernel<<<ablk, 256, 0, stream>>>(h1, offs, cnt, csr, agg, n);
    // layer 2 writes h2 in place into agg
    layer_mfma_kernel<<<nblk, 256, 0, stream>>>(agg, h1, WT2h, WT2l, b2, agg, n);

    proj_kernel<<<nblk, 256, 0, stream>>>(agg, Wout, bout, out, n);
}

// Round 6
// 401.370 us; speedup vs baseline: 5.8372x; 1.3851x over previous
//
#include <hip/hip_runtime.h>

#define DD 128
#define CC 64
#define BKW 512            // nodes per bucket
#define NPB 4096           // edges per phase-B block

typedef __attribute__((ext_vector_type(8))) short short8v;
typedef __attribute__((ext_vector_type(4))) float f32x4;

static __device__ inline ushort f2bf_rne(float f) {
    unsigned u = __float_as_uint(f);
    unsigned r = (u + 0x7FFFu + ((u >> 16) & 1u)) >> 16;
    return (ushort)r;
}
static __device__ inline float bf2f(ushort h) {
    return __uint_as_float(((unsigned)h) << 16);
}

// ================= degree count =================
__global__ __launch_bounds__(256) void cnt_kernel(const int* __restrict__ ei,
                                                  int* __restrict__ cnt, int E) {
    int e = blockIdx.x * 256 + threadIdx.x;
    if (e < E) atomicAdd(&cnt[ei[E + e]], 1);
}

// ================= exclusive scan over cnt -> offs =================
__global__ __launch_bounds__(256) void scan1_kernel(const int* __restrict__ cnt,
                                                    int* __restrict__ offs,
                                                    int* __restrict__ bsum, int n) {
    __shared__ int s[256];
    const int t = threadIdx.x;
    const int base = blockIdx.x * 2048 + t * 8;
    int v[8];
    int sum = 0;
    #pragma unroll
    for (int j = 0; j < 8; ++j) {
        int idx = base + j;
        v[j] = (idx < n) ? cnt[idx] : 0;
        sum += v[j];
    }
    s[t] = sum;
    __syncthreads();
    for (int off = 1; off < 256; off <<= 1) {
        int xv = 0;
        if (t >= off) xv = s[t - off];
        __syncthreads();
        if (t >= off) s[t] += xv;
        __syncthreads();
    }
    int run = s[t] - sum;
    #pragma unroll
    for (int j = 0; j < 8; ++j) {
        int idx = base + j;
        if (idx < n) offs[idx] = run;
        run += v[j];
    }
    if (t == 255) bsum[blockIdx.x] = s[255];
}

__global__ void scan2_kernel(const int* __restrict__ bsum,
                             int* __restrict__ bscan, int nb) {
    if (threadIdx.x == 0 && blockIdx.x == 0) {
        int acc = 0;
        for (int i = 0; i < nb; ++i) { bscan[i] = acc; acc += bsum[i]; }
    }
}

__global__ __launch_bounds__(256) void scan_fix_kernel(int* __restrict__ offs,
                                                       const int* __restrict__ bscan,
                                                       int n) {
    int i = blockIdx.x * 256 + threadIdx.x;
    if (i < n) offs[i] += bscan[i >> 11];
}

__global__ void binit_kernel(const int* __restrict__ offs,
                             int* __restrict__ bcur, int nbuck) {
    int b = blockIdx.x * 64 + threadIdx.x;
    if (b < nbuck) bcur[b] = offs[b * BKW];
}

// ================= phase B: bin edges by bucket (coalesced pair writes) =====
__global__ __launch_bounds__(256) void binA_kernel(const int* __restrict__ ei,
                                                   int* __restrict__ bcur,
                                                   uint2* __restrict__ ebuf, int E) {
    __shared__ int sRun[256];    // scan buf, then per-bucket run start
    __shared__ int sRel[256];    // staging cursor
    __shared__ int sBase[256];   // global base per bucket
    __shared__ uint2 sPair[NPB];
    const int t = threadIdx.x;
    const int e0 = blockIdx.x * NPB;
    const int cntE = min(NPB, E - e0);

    // pass 1: histogram
    __shared__ int sHist[256];
    sHist[t] = 0;
    __syncthreads();
    for (int j = t; j < cntE; j += 256) {
        int dst = ei[E + e0 + j];
        atomicAdd(&sHist[dst >> 9], 1);
    }
    __syncthreads();
    int h = sHist[t];
    // inclusive scan over 256
    sRun[t] = h;
    __syncthreads();
    for (int off = 1; off < 256; off <<= 1) {
        int v = 0;
        if (t >= off) v = sRun[t - off];
        __syncthreads();
        if (t >= off) sRun[t] += v;
        __syncthreads();
    }
    int runstart = sRun[t] - h;
    int base = 0;
    if (h > 0) base = atomicAdd(&bcur[t], h);
    sRun[t] = runstart;
    sRel[t] = runstart;
    sBase[t] = base;
    __syncthreads();
    // pass 2: stage pairs bucket-sorted in LDS
    for (int j = t; j < cntE; j += 256) {
        int src = ei[e0 + j];
        int dst = ei[E + e0 + j];
        int b = dst >> 9;
        int slot = atomicAdd(&sRel[b], 1);
        sPair[slot] = make_uint2((unsigned)src, (unsigned)dst);
    }
    __syncthreads();
    // pass 3: write runs out (coalesced within runs)
    for (int s = t; s < cntE; s += 256) {
        uint2 p = sPair[s];
        int b = (int)(p.y >> 9);
        int gpos = sBase[b] + (s - sRun[b]);
        ebuf[gpos] = p;
    }
}

// ================= phase C: per-bucket scatter with LDS cursors =============
__global__ __launch_bounds__(256) void binB_kernel(const uint2* __restrict__ ebuf,
                                                   const int* __restrict__ offs,
                                                   int* __restrict__ csr,
                                                   int n, int E) {
    __shared__ int sOffs[BKW];
    __shared__ int sCur[BKW];
    const int t = threadIdx.x;
    const int node0 = blockIdx.x * BKW;
    const int node1 = min(n, node0 + BKW);
    for (int i = t; i < node1 - node0; i += 256) {
        sOffs[i] = offs[node0 + i];
        sCur[i] = 0;
    }
    __syncthreads();
    const int start = offs[node0];
    const int end = (node1 < n) ? offs[node1] : E;
    for (int j = start + t; j < end; j += 256) {
        uint2 p = ebuf[j];
        int d = (int)p.y - node0;
        int r = atomicAdd(&sCur[d], 1);
        csr[sOffs[d] + r] = (int)p.x;
    }
}

// ================= f32 -> bf16 hi plane =================
__global__ __launch_bounds__(256) void xsplit_kernel(const float* __restrict__ x,
                                                     ushort* __restrict__ xh,
                                                     int total8) {
    int i = blockIdx.x * 256 + threadIdx.x;    // 8 elems per thread
    if (i >= total8) return;
    float4 a = ((const float4*)x)[2 * i];
    float4 b = ((const float4*)x)[2 * i + 1];
    ushort r[8] = {f2bf_rne(a.x), f2bf_rne(a.y), f2bf_rne(a.z), f2bf_rne(a.w),
                   f2bf_rne(b.x), f2bf_rne(b.y), f2bf_rne(b.z), f2bf_rne(b.w)};
    uint4 o;
    o.x = (uint)r[0] | ((uint)r[1] << 16);
    o.y = (uint)r[2] | ((uint)r[3] << 16);
    o.z = (uint)r[4] | ((uint)r[5] << 16);
    o.w = (uint)r[6] | ((uint)r[7] << 16);
    ((uint4*)xh)[i] = o;
}

// ================= CSR gather-aggregate (bf16 hi plane, f32 accum) ==========
__global__ __launch_bounds__(256) void csr_agg_bf_kernel(
    const ushort* __restrict__ xh, const int* __restrict__ offs,
    const int* __restrict__ cnt, const int* __restrict__ csr,
    float* __restrict__ mean, int n) {
    int node = blockIdx.x * 4 + (threadIdx.x >> 6);
    if (node >= n) return;
    const int lane = threadIdx.x & 63;
    const int start = offs[node];
    const int c = cnt[node];
    float ax = 0.f, ay = 0.f;
    int j = 0;
    for (; j + 4 <= c; j += 4) {
        int s0 = csr[start + j];
        int s1 = csr[start + j + 1];
        int s2 = csr[start + j + 2];
        int s3 = csr[start + j + 3];
        uint u0 = *(const uint*)(xh + (size_t)s0 * DD + 2 * lane);
        uint u1 = *(const uint*)(xh + (size_t)s1 * DD + 2 * lane);
        uint u2 = *(const uint*)(xh + (size_t)s2 * DD + 2 * lane);
        uint u3 = *(const uint*)(xh + (size_t)s3 * DD + 2 * lane);
        ax += bf2f((ushort)(u0 & 0xffffu)) + bf2f((ushort)(u1 & 0xffffu))
            + bf2f((ushort)(u2 & 0xffffu)) + bf2f((ushort)(u3 & 0xffffu));
        ay += bf2f((ushort)(u0 >> 16)) + bf2f((ushort)(u1 >> 16))
            + bf2f((ushort)(u2 >> 16)) + bf2f((ushort)(u3 >> 16));
    }
    for (; j < c; ++j) {
        int s = csr[start + j];
        uint u = *(const uint*)(xh + (size_t)s * DD + 2 * lane);
        ax += bf2f((ushort)(u & 0xffffu));
        ay += bf2f((ushort)(u >> 16));
    }
    float inv = 1.0f / fmaxf((float)c, 1.0f);
    float2 o; o.x = ax * inv; o.y = ay * inv;
    *(float2*)(mean + (size_t)node * DD + 2 * lane) = o;
}

// ====== weight prep: WT_hi/lo[c][k] (k: 0..127 = Wl, 128..255 = Wr) ======
__global__ __launch_bounds__(256) void wsplit_kernel(
    const float* __restrict__ Wl, const float* __restrict__ Wr,
    ushort* __restrict__ WT_hi, ushort* __restrict__ WT_lo) {
    int idx = blockIdx.x * 256 + threadIdx.x;   // c*256 + k
    if (idx >= DD * 256) return;
    int c = idx >> 8, k = idx & 255;
    float v = (k < DD) ? Wl[k * DD + c] : Wr[(k - DD) * DD + c];
    ushort h = f2bf_rne(v);
    ushort lo = f2bf_rne(v - bf2f(h));
    WT_hi[idx] = h;
    WT_lo[idx] = lo;
}

// ================= MFMA SAGE layer =================
// out = relu([mean | root] @ WT^T + bias). K=256 in 8 slices of 32.
// XPLANES: root term supplied as pre-split bf16 hi/lo planes (xh/xl);
//          else f32 xf split on the fly.
// OUTPL:   write output as bf16 hi/lo planes (outH/outL); else f32 outF.
// hi/lo split => ~f32 precision: acc += ah*bh + al*bh + ah*bl.
// NOTE: outF may alias mean (layer 2 in place): blocks read only their own
// 64 rows during the K loop and store only in the epilogue -> safe.
template <bool XPLANES, bool OUTPL>
__global__ __launch_bounds__(256) void layer_mfma_kernel(
    const float* mean, const float* xf,
    const ushort* __restrict__ xh, const ushort* __restrict__ xl,
    const ushort* __restrict__ WT_hi, const ushort* __restrict__ WT_lo,
    const float* __restrict__ bias,
    float* outF, ushort* __restrict__ outH, ushort* __restrict__ outL, int n) {
    __shared__ ushort sAh[64][40], sAl[64][40];     // padded stride 80B
    __shared__ ushort sBh[128][40], sBl[128][40];
    const int tid = threadIdx.x;
    const int w = tid >> 6;
    const int l = tid & 63;
    const int row0 = blockIdx.x * 64;

    // staging roles
    const int ar  = tid >> 2;            // A row 0..63
    const int akq = (tid & 3) * 8;       // A k offset within slice
    const int arowg = min(row0 + ar, n - 1);
    const int bc  = tid >> 1;            // B col 0..127
    const int bkh = (tid & 1) * 16;      // B k offset within slice

    // frag roles
    const int arow = w * 16 + (l & 15);
    const int kb   = (l >> 4) * 8;
    const int lcol = l & 15;

    f32x4 acc[8];
    #pragma unroll
    for (int t = 0; t < 8; ++t) acc[t] = (f32x4){0.f, 0.f, 0.f, 0.f};

    for (int s = 0; s < 8; ++s) {
        const int k0 = s * 32;
        short8v ah_w, al_w;
        if (s < 4 || !XPLANES) {
            const float* Asrc = (s < 4) ? (mean + (size_t)arowg * DD + k0)
                                        : (xf + (size_t)arowg * DD + (k0 - DD));
            float4 v0 = *(const float4*)(Asrc + akq);
            float4 v1 = *(const float4*)(Asrc + akq + 4);
            float vv[8] = {v0.x, v0.y, v0.z, v0.w, v1.x, v1.y, v1.z, v1.w};
            #pragma unroll
            for (int j = 0; j < 8; ++j) {
                ushort hh = f2bf_rne(vv[j]);
                ah_w[j] = (short)hh;
                al_w[j] = (short)f2bf_rne(vv[j] - bf2f(hh));
            }
        } else {
            ah_w = *(const short8v*)(xh + (size_t)arowg * DD + (k0 - DD) + akq);
            al_w = *(const short8v*)(xl + (size_t)arowg * DD + (k0 - DD) + akq);
        }
        const ushort* bhp = WT_hi + bc * 256 + k0 + bkh;
        const ushort* blp = WT_lo + bc * 256 + k0 + bkh;
        short8v bh0 = *(const short8v*)bhp;
        short8v bh1 = *(const short8v*)(bhp + 8);
        short8v bl0 = *(const short8v*)blp;
        short8v bl1 = *(const short8v*)(blp + 8);

        __syncthreads();   // previous slice's frag reads complete
        *(short8v*)&sAh[ar][akq] = ah_w;
        *(short8v*)&sAl[ar][akq] = al_w;
        *(short8v*)&sBh[bc][bkh]     = bh0;
        *(short8v*)&sBh[bc][bkh + 8] = bh1;
        *(short8v*)&sBl[bc][bkh]     = bl0;
        *(short8v*)&sBl[bc][bkh + 8] = bl1;
        __syncthreads();

        short8v ah = *(const short8v*)&sAh[arow][kb];
        short8v al = *(const short8v*)&sAl[arow][kb];
        #pragma unroll
        for (int t = 0; t < 8; ++t) {
            short8v bh = *(const short8v*)&sBh[t * 16 + lcol][kb];
            short8v bl = *(const short8v*)&sBl[t * 16 + lcol][kb];
            acc[t] = __builtin_amdgcn_mfma_f32_16x16x32_bf16(ah, bh, acc[t], 0, 0, 0);
            acc[t] = __builtin_amdgcn_mfma_f32_16x16x32_bf16(al, bh, acc[t], 0, 0, 0);
            acc[t] = __builtin_amdgcn_mfma_f32_16x16x32_bf16(ah, bl, acc[t], 0, 0, 0);
        }
    }

    // epilogue: C/D layout col=lane&15, row=4*(lane>>4)+reg
    const int orow0 = row0 + w * 16 + (l >> 4) * 4;
    #pragma unroll
    for (int t = 0; t < 8; ++t) {
        const int col = t * 16 + lcol;
        const float b = bias[col];
        #pragma unroll
        for (int r = 0; r < 4; ++r) {
            int row = orow0 + r;
            if (row < n) {
                float o = fmaxf(acc[t][r] + b, 0.f);
                if (OUTPL) {
                    ushort oh = f2bf_rne(o);
                    outH[(size_t)row * DD + col] = oh;
                    outL[(size_t)row * DD + col] = f2bf_rne(o - bf2f(oh));
                } else {
                    outF[(size_t)row * DD + col] = o;
                }
            }
        }
    }
}

// ================= output projection: out = h2 @ Wout + bout =================
__global__ __launch_bounds__(256) void proj_kernel(
    const float* __restrict__ h2, const float* __restrict__ Wout,
    const float* __restrict__ bout, float* __restrict__ out, int n) {
    __shared__ float sWo[DD][CC];
    const int tid = threadIdx.x;
    for (int i = tid; i < DD * CC / 4; i += 256) {
        ((float4*)sWo)[i] = ((const float4*)Wout)[i];
    }
    __syncthreads();
    const int prow = tid >> 2;
    const int oc = (tid & 3) * 16;
    const int row = blockIdx.x * 64 + prow;
    const int rowc = min(row, n - 1);
    const float* hrow = h2 + (size_t)rowc * DD;
    float po[16];
    #pragma unroll
    for (int q = 0; q < 4; ++q) {
        float4 b4 = *(const float4*)(bout + oc + q * 4);
        po[q * 4 + 0] = b4.x; po[q * 4 + 1] = b4.y;
        po[q * 4 + 2] = b4.z; po[q * 4 + 3] = b4.w;
    }
    for (int k = 0; k < DD; k += 4) {
        float4 h4 = *(const float4*)(hrow + k);
        #pragma unroll
        for (int j = 0; j < 4; ++j) {
            float hv = ((const float*)&h4)[j];
            const float* wrow = &sWo[k + j][oc];
            #pragma unroll
            for (int q = 0; q < 4; ++q) {
                float4 w4 = *(const float4*)(wrow + q * 4);
                po[q * 4 + 0] += hv * w4.x;
                po[q * 4 + 1] += hv * w4.y;
                po[q * 4 + 2] += hv * w4.z;
                po[q * 4 + 3] += hv * w4.w;
            }
        }
    }
    if (row < n) {
        #pragma unroll
        for (int q = 0; q < 4; ++q) {
            float4 o;
            o.x = po[q * 4 + 0]; o.y = po[q * 4 + 1];
            o.z = po[q * 4 + 2]; o.w = po[q * 4 + 3];
            *(float4*)(out + (size_t)row * CC + oc + q * 4) = o;
        }
    }
}

extern "C" void kernel_launch(void* const* d_in, const int* in_sizes, int n_in,
                              void* d_out, int out_size, void* d_ws, size_t ws_size,
                              hipStream_t stream) {
    const float* x    = (const float*)d_in[0];
    const int*   ei   = (const int*)d_in[1];
    const float* W1l  = (const float*)d_in[2];
    const float* b1   = (const float*)d_in[3];
    const float* W1r  = (const float*)d_in[4];
    const float* W2l  = (const float*)d_in[5];
    const float* b2   = (const float*)d_in[6];
    const float* W2r  = (const float*)d_in[7];
    const float* Wout = (const float*)d_in[8];
    const float* bout = (const float*)d_in[9];
    float* out = (float*)d_out;
    const int n = in_sizes[0] / DD;       // 100000
    const int E = in_sizes[1] / 2;        // 1600000

    const int NB_SCAN = (n + 2047) / 2048;
    const int NBUCK = (n + BKW - 1) / BKW;

    // workspace layout (all offsets 256B-aligned)
    int* cnt   = (int*)d_ws;                              // 100352
    int* offs  = cnt + 100352;                            // 100352
    int* bsum  = offs + 100352;                           // 256
    int* bscan = bsum + 256;                              // 256
    int* bcur  = bscan + 256;                             // 256
    int* csr   = bcur + 256;                              // E
    uint2* ebuf = (uint2*)(csr + 1600000);                // E pairs (12.8MB)
    ushort* xh  = (ushort*)ebuf;                          // union: n*128 (25.6MB) >= ebuf
    float* mean = (float*)((char*)ebuf + (size_t)n * DD * 2);   // n*128 f32
    ushort* h1h = (ushort*)(mean + (size_t)n * DD);       // n*128 bf16
    ushort* h1l = h1h + (size_t)n * DD;                   // n*128 bf16
    ushort* WT1h = h1l + (size_t)n * DD;                  // 128*256 each
    ushort* WT1l = WT1h + DD * 256;
    ushort* WT2h = WT1l + DD * 256;
    ushort* WT2l = WT2h + DD * 256;

    hipMemsetAsync(cnt, 0, sizeof(int) * (size_t)n, stream);
    cnt_kernel<<<(E + 255) / 256, 256, 0, stream>>>(ei, cnt, E);
    scan1_kernel<<<NB_SCAN, 256, 0, stream>>>(cnt, offs, bsum, n);
    scan2_kernel<<<1, 64, 0, stream>>>(bsum, bscan, NB_SCAN);
    scan_fix_kernel<<<(n + 255) / 256, 256, 0, stream>>>(offs, bscan, n);
    binit_kernel<<<(NBUCK + 63) / 64, 64, 0, stream>>>(offs, bcur, NBUCK);
    binA_kernel<<<(E + NPB - 1) / NPB, 256, 0, stream>>>(ei, bcur, ebuf, E);
    binB_kernel<<<NBUCK, 256, 0, stream>>>(ebuf, offs, csr, n, E);

    wsplit_kernel<<<DD, 256, 0, stream>>>(W1l, W1r, WT1h, WT1l);
    wsplit_kernel<<<DD, 256, 0, stream>>>(W2l, W2r, WT2h, WT2l);

    // ebuf dead now -> reuse region as xh
    xsplit_kernel<<<(n * DD / 8 + 255) / 256, 256, 0, stream>>>(x, xh, n * DD / 8);

    const int nblk = (n + 63) / 64;
    const int ablk = (n + 3) / 4;

    csr_agg_bf_kernel<<<ablk, 256, 0, stream>>>(xh, offs, cnt, csr, mean, n);
    layer_mfma_kernel<false, true><<<nblk, 256, 0, stream>>>(
        mean, x, (const ushort*)nullptr, (const ushort*)nullptr,
        WT1h, WT1l, b1, (float*)nullptr, h1h, h1l, n);

    csr_agg_bf_kernel<<<ablk, 256, 0, stream>>>(h1h, offs, cnt, csr, mean, n);
    // layer 2 writes h2 in place into mean
    layer_mfma_kernel<true, false><<<nblk, 256, 0, stream>>>(
        mean, (const float*)nullptr, h1h, h1l,
        WT2h, WT2l, b2, mean, (ushort*)nullptr, (ushort*)nullptr, n);

    proj_kernel<<<nblk, 256, 0, stream>>>(mean, Wout, bout, out, n);
}

// Round 7
// 380.472 us; speedup vs baseline: 6.1578x; 1.0549x over previous
//
#include <hip/hip_runtime.h>

#define DD 128
#define CC 64
#define BKW 512            // nodes per bucket
#define NPB 4096           // edges per phase-B block

typedef __attribute__((ext_vector_type(8))) short short8v;
typedef __attribute__((ext_vector_type(4))) float f32x4;

static __device__ inline ushort f2bf_rne(float f) {
    unsigned u = __float_as_uint(f);
    unsigned r = (u + 0x7FFFu + ((u >> 16) & 1u)) >> 16;
    return (ushort)r;
}
static __device__ inline float bf2f(ushort h) {
    return __uint_as_float(((unsigned)h) << 16);
}
static __device__ inline float bflo(uint u) {        // low bf16 of packed pair
    return __uint_as_float(u << 16);
}
static __device__ inline float bfhi(uint u) {        // high bf16 of packed pair
    return __uint_as_float(u & 0xffff0000u);
}

// ================= degree count =================
__global__ __launch_bounds__(256) void cnt_kernel(const int* __restrict__ ei,
                                                  int* __restrict__ cnt, int E) {
    int e = blockIdx.x * 256 + threadIdx.x;
    if (e < E) atomicAdd(&cnt[ei[E + e]], 1);
}

// ================= exclusive scan over cnt -> offs =================
__global__ __launch_bounds__(256) void scan1_kernel(const int* __restrict__ cnt,
                                                    int* __restrict__ offs,
                                                    int* __restrict__ bsum, int n) {
    __shared__ int s[256];
    const int t = threadIdx.x;
    const int base = blockIdx.x * 2048 + t * 8;
    int v[8];
    int sum = 0;
    #pragma unroll
    for (int j = 0; j < 8; ++j) {
        int idx = base + j;
        v[j] = (idx < n) ? cnt[idx] : 0;
        sum += v[j];
    }
    s[t] = sum;
    __syncthreads();
    for (int off = 1; off < 256; off <<= 1) {
        int xv = 0;
        if (t >= off) xv = s[t - off];
        __syncthreads();
        if (t >= off) s[t] += xv;
        __syncthreads();
    }
    int run = s[t] - sum;
    #pragma unroll
    for (int j = 0; j < 8; ++j) {
        int idx = base + j;
        if (idx < n) offs[idx] = run;
        run += v[j];
    }
    if (t == 255) bsum[blockIdx.x] = s[255];
}

__global__ void scan2_kernel(const int* __restrict__ bsum,
                             int* __restrict__ bscan, int nb) {
    if (threadIdx.x == 0 && blockIdx.x == 0) {
        int acc = 0;
        for (int i = 0; i < nb; ++i) { bscan[i] = acc; acc += bsum[i]; }
    }
}

__global__ __launch_bounds__(256) void scan_fix_kernel(int* __restrict__ offs,
                                                       const int* __restrict__ bscan,
                                                       int n) {
    int i = blockIdx.x * 256 + threadIdx.x;
    if (i < n) offs[i] += bscan[i >> 11];
}

__global__ void binit_kernel(const int* __restrict__ offs,
                             int* __restrict__ bcur, int nbuck) {
    int b = blockIdx.x * 64 + threadIdx.x;
    if (b < nbuck) bcur[b] = offs[b * BKW];
}

// ================= phase B: bin edges by bucket (coalesced pair writes) =====
__global__ __launch_bounds__(256) void binA_kernel(const int* __restrict__ ei,
                                                   int* __restrict__ bcur,
                                                   uint2* __restrict__ ebuf, int E) {
    __shared__ int sRun[256];
    __shared__ int sRel[256];
    __shared__ int sBase[256];
    __shared__ uint2 sPair[NPB];
    __shared__ int sHist[256];
    const int t = threadIdx.x;
    const int e0 = blockIdx.x * NPB;
    const int cntE = min(NPB, E - e0);

    sHist[t] = 0;
    __syncthreads();
    for (int j = t; j < cntE; j += 256) {
        int dst = ei[E + e0 + j];
        atomicAdd(&sHist[dst >> 9], 1);
    }
    __syncthreads();
    int h = sHist[t];
    sRun[t] = h;
    __syncthreads();
    for (int off = 1; off < 256; off <<= 1) {
        int v = 0;
        if (t >= off) v = sRun[t - off];
        __syncthreads();
        if (t >= off) sRun[t] += v;
        __syncthreads();
    }
    int runstart = sRun[t] - h;
    int base = 0;
    if (h > 0) base = atomicAdd(&bcur[t], h);
    sRun[t] = runstart;
    sRel[t] = runstart;
    sBase[t] = base;
    __syncthreads();
    for (int j = t; j < cntE; j += 256) {
        int src = ei[e0 + j];
        int dst = ei[E + e0 + j];
        int b = dst >> 9;
        int slot = atomicAdd(&sRel[b], 1);
        sPair[slot] = make_uint2((unsigned)src, (unsigned)dst);
    }
    __syncthreads();
    for (int s = t; s < cntE; s += 256) {
        uint2 p = sPair[s];
        int b = (int)(p.y >> 9);
        int gpos = sBase[b] + (s - sRun[b]);
        ebuf[gpos] = p;
    }
}

// ================= phase C: per-bucket scatter with LDS cursors =============
__global__ __launch_bounds__(256) void binB_kernel(const uint2* __restrict__ ebuf,
                                                   const int* __restrict__ offs,
                                                   int* __restrict__ csr,
                                                   int n, int E) {
    __shared__ int sOffs[BKW];
    __shared__ int sCur[BKW];
    const int t = threadIdx.x;
    const int node0 = blockIdx.x * BKW;
    const int node1 = min(n, node0 + BKW);
    for (int i = t; i < node1 - node0; i += 256) {
        sOffs[i] = offs[node0 + i];
        sCur[i] = 0;
    }
    __syncthreads();
    const int start = offs[node0];
    const int end = (node1 < n) ? offs[node1] : E;
    for (int j = start + t; j < end; j += 256) {
        uint2 p = ebuf[j];
        int d = (int)p.y - node0;
        int r = atomicAdd(&sCur[d], 1);
        csr[sOffs[d] + r] = (int)p.x;
    }
}

// ================= f32 -> bf16 hi plane =================
__global__ __launch_bounds__(256) void xsplit_kernel(const float* __restrict__ x,
                                                     ushort* __restrict__ xh,
                                                     int total8) {
    int i = blockIdx.x * 256 + threadIdx.x;    // 8 elems per thread
    if (i >= total8) return;
    float4 a = ((const float4*)x)[2 * i];
    float4 b = ((const float4*)x)[2 * i + 1];
    ushort r[8] = {f2bf_rne(a.x), f2bf_rne(a.y), f2bf_rne(a.z), f2bf_rne(a.w),
                   f2bf_rne(b.x), f2bf_rne(b.y), f2bf_rne(b.z), f2bf_rne(b.w)};
    uint4 o;
    o.x = (uint)r[0] | ((uint)r[1] << 16);
    o.y = (uint)r[2] | ((uint)r[3] << 16);
    o.z = (uint)r[4] | ((uint)r[5] << 16);
    o.w = (uint)r[6] | ((uint)r[7] << 16);
    ((uint4*)xh)[i] = o;
}

// ====== CSR gather-aggregate: 4 neighbors/wave-iter, uint4 (16B) lane loads =====
// lane = (sub=lane>>4: neighbor slot, li=lane&15: 8-dim chunk).
// Cross-lane xor-reduce(16,32) sums the 4 slots; sub==0 lanes write bf16 mean.
__global__ __launch_bounds__(256) void csr_agg4_kernel(
    const ushort* __restrict__ xh, const int* __restrict__ offs,
    const int* __restrict__ cnt, const int* __restrict__ csr,
    ushort* __restrict__ meanH, int n) {
    int node = blockIdx.x * 4 + (threadIdx.x >> 6);
    if (node >= n) return;
    const int lane = threadIdx.x & 63;
    const int sub = lane >> 4;
    const int li = lane & 15;
    const int start = offs[node];
    const int c = cnt[node];
    float a[8] = {0.f, 0.f, 0.f, 0.f, 0.f, 0.f, 0.f, 0.f};
    const int cmain = c & ~3;
    int j = 0;
    for (; j < cmain; j += 4) {
        int s = csr[start + j + sub];
        uint4 u = *(const uint4*)(xh + (size_t)s * DD + li * 8);
        a[0] += bflo(u.x); a[1] += bfhi(u.x);
        a[2] += bflo(u.y); a[3] += bfhi(u.y);
        a[4] += bflo(u.z); a[5] += bfhi(u.z);
        a[6] += bflo(u.w); a[7] += bfhi(u.w);
    }
    if (j + sub < c) {
        int s = csr[start + j + sub];
        uint4 u = *(const uint4*)(xh + (size_t)s * DD + li * 8);
        a[0] += bflo(u.x); a[1] += bfhi(u.x);
        a[2] += bflo(u.y); a[3] += bfhi(u.y);
        a[4] += bflo(u.z); a[5] += bfhi(u.z);
        a[6] += bflo(u.w); a[7] += bfhi(u.w);
    }
    #pragma unroll
    for (int k = 0; k < 8; ++k) {
        a[k] += __shfl_xor(a[k], 16);
        a[k] += __shfl_xor(a[k], 32);
    }
    if (sub == 0) {
        float inv = 1.0f / fmaxf((float)c, 1.0f);
        short8v o;
        #pragma unroll
        for (int k = 0; k < 8; ++k) o[k] = (short)f2bf_rne(a[k] * inv);
        *(short8v*)(meanH + (size_t)node * DD + li * 8) = o;
    }
}

// ====== weight prep: WT_hi/lo[c][k] (k: 0..127 = Wl, 128..255 = Wr) ======
__global__ __launch_bounds__(256) void wsplit_kernel(
    const float* __restrict__ Wl, const float* __restrict__ Wr,
    ushort* __restrict__ WT_hi, ushort* __restrict__ WT_lo) {
    int idx = blockIdx.x * 256 + threadIdx.x;   // c*256 + k
    if (idx >= DD * 256) return;
    int c = idx >> 8, k = idx & 255;
    float v = (k < DD) ? Wl[k * DD + c] : Wr[(k - DD) * DD + c];
    ushort h = f2bf_rne(v);
    ushort lo = f2bf_rne(v - bf2f(h));
    WT_hi[idx] = h;
    WT_lo[idx] = lo;
}

// ================= MFMA SAGE layer =================
// out = relu([meanH | root] @ WT^T + bias). K=256 in 8 slices of 32.
// Phase A (s=0..3): A = meanH bf16 plane (lo=0 -> 2 MFMAs/tile).
// Phase B (s=4..7): root term; ROOTPL ? bf16 hi/lo planes : f32 split on fly.
// OUTMODE 1: write hi+lo planes. OUTMODE 2: hi plane only (may alias meanH:
// blocks read only their own 64 rows, store only in epilogue -> safe).
template <bool ROOTPL, int OUTMODE>
__global__ __launch_bounds__(256) void layer_mfma_kernel(
    const ushort* meanH, const float* __restrict__ xf,
    const ushort* __restrict__ rh, const ushort* __restrict__ rl,
    const ushort* __restrict__ WT_hi, const ushort* __restrict__ WT_lo,
    const float* __restrict__ bias,
    ushort* outH, ushort* __restrict__ outL, int n) {
    __shared__ ushort sAh[64][40], sAl[64][40];
    __shared__ ushort sBh[128][40], sBl[128][40];
    const int tid = threadIdx.x;
    const int w = tid >> 6;
    const int l = tid & 63;
    const int row0 = blockIdx.x * 64;

    const int ar  = tid >> 2;            // A row 0..63
    const int akq = (tid & 3) * 8;       // A k offset within slice
    const int arowg = min(row0 + ar, n - 1);
    const int bc  = tid >> 1;            // B col 0..127
    const int bkh = (tid & 1) * 16;      // B k offset within slice

    const int arow = w * 16 + (l & 15);
    const int kb   = (l >> 4) * 8;
    const int lcol = l & 15;

    f32x4 acc[8];
    #pragma unroll
    for (int t = 0; t < 8; ++t) acc[t] = (f32x4){0.f, 0.f, 0.f, 0.f};

    // ---- phase A: mean (bf16 plane, lo = 0) ----
    for (int s = 0; s < 4; ++s) {
        const int k0 = s * 32;
        short8v ah_w = *(const short8v*)(meanH + (size_t)arowg * DD + k0 + akq);
        const ushort* bhp = WT_hi + bc * 256 + k0 + bkh;
        const ushort* blp = WT_lo + bc * 256 + k0 + bkh;
        short8v bh0 = *(const short8v*)bhp;
        short8v bh1 = *(const short8v*)(bhp + 8);
        short8v bl0 = *(const short8v*)blp;
        short8v bl1 = *(const short8v*)(blp + 8);

        __syncthreads();
        *(short8v*)&sAh[ar][akq] = ah_w;
        *(short8v*)&sBh[bc][bkh]     = bh0;
        *(short8v*)&sBh[bc][bkh + 8] = bh1;
        *(short8v*)&sBl[bc][bkh]     = bl0;
        *(short8v*)&sBl[bc][bkh + 8] = bl1;
        __syncthreads();

        short8v ah = *(const short8v*)&sAh[arow][kb];
        #pragma unroll
        for (int t = 0; t < 8; ++t) {
            short8v bh = *(const short8v*)&sBh[t * 16 + lcol][kb];
            short8v bl = *(const short8v*)&sBl[t * 16 + lcol][kb];
            acc[t] = __builtin_amdgcn_mfma_f32_16x16x32_bf16(ah, bh, acc[t], 0, 0, 0);
            acc[t] = __builtin_amdgcn_mfma_f32_16x16x32_bf16(ah, bl, acc[t], 0, 0, 0);
        }
    }
    // ---- phase B: root term (hi/lo) ----
    for (int s = 4; s < 8; ++s) {
        const int k0 = s * 32;
        short8v ah_w, al_w;
        if (ROOTPL) {
            ah_w = *(const short8v*)(rh + (size_t)arowg * DD + (k0 - DD) + akq);
            al_w = *(const short8v*)(rl + (size_t)arowg * DD + (k0 - DD) + akq);
        } else {
            const float* Asrc = xf + (size_t)arowg * DD + (k0 - DD);
            float4 v0 = *(const float4*)(Asrc + akq);
            float4 v1 = *(const float4*)(Asrc + akq + 4);
            float vv[8] = {v0.x, v0.y, v0.z, v0.w, v1.x, v1.y, v1.z, v1.w};
            #pragma unroll
            for (int j = 0; j < 8; ++j) {
                ushort hh = f2bf_rne(vv[j]);
                ah_w[j] = (short)hh;
                al_w[j] = (short)f2bf_rne(vv[j] - bf2f(hh));
            }
        }
        const ushort* bhp = WT_hi + bc * 256 + k0 + bkh;
        const ushort* blp = WT_lo + bc * 256 + k0 + bkh;
        short8v bh0 = *(const short8v*)bhp;
        short8v bh1 = *(const short8v*)(bhp + 8);
        short8v bl0 = *(const short8v*)blp;
        short8v bl1 = *(const short8v*)(blp + 8);

        __syncthreads();
        *(short8v*)&sAh[ar][akq] = ah_w;
        *(short8v*)&sAl[ar][akq] = al_w;
        *(short8v*)&sBh[bc][bkh]     = bh0;
        *(short8v*)&sBh[bc][bkh + 8] = bh1;
        *(short8v*)&sBl[bc][bkh]     = bl0;
        *(short8v*)&sBl[bc][bkh + 8] = bl1;
        __syncthreads();

        short8v ah = *(const short8v*)&sAh[arow][kb];
        short8v al = *(const short8v*)&sAl[arow][kb];
        #pragma unroll
        for (int t = 0; t < 8; ++t) {
            short8v bh = *(const short8v*)&sBh[t * 16 + lcol][kb];
            short8v bl = *(const short8v*)&sBl[t * 16 + lcol][kb];
            acc[t] = __builtin_amdgcn_mfma_f32_16x16x32_bf16(ah, bh, acc[t], 0, 0, 0);
            acc[t] = __builtin_amdgcn_mfma_f32_16x16x32_bf16(al, bh, acc[t], 0, 0, 0);
            acc[t] = __builtin_amdgcn_mfma_f32_16x16x32_bf16(ah, bl, acc[t], 0, 0, 0);
        }
    }

    // epilogue: C/D layout col=lane&15, row=4*(lane>>4)+reg
    const int orow0 = row0 + w * 16 + (l >> 4) * 4;
    #pragma unroll
    for (int t = 0; t < 8; ++t) {
        const int col = t * 16 + lcol;
        const float b = bias[col];
        #pragma unroll
        for (int r = 0; r < 4; ++r) {
            int row = orow0 + r;
            if (row < n) {
                float o = fmaxf(acc[t][r] + b, 0.f);
                ushort oh = f2bf_rne(o);
                outH[(size_t)row * DD + col] = oh;
                if (OUTMODE == 1)
                    outL[(size_t)row * DD + col] = f2bf_rne(o - bf2f(oh));
            }
        }
    }
}

// ================= output projection: out = h2h @ Wout + bout =================
__global__ __launch_bounds__(256) void proj_kernel(
    const ushort* __restrict__ h2, const float* __restrict__ Wout,
    const float* __restrict__ bout, float* __restrict__ out, int n) {
    __shared__ float sWo[DD][CC];
    const int tid = threadIdx.x;
    for (int i = tid; i < DD * CC / 4; i += 256) {
        ((float4*)sWo)[i] = ((const float4*)Wout)[i];
    }
    __syncthreads();
    const int prow = tid >> 2;
    const int oc = (tid & 3) * 16;
    const int row = blockIdx.x * 64 + prow;
    const int rowc = min(row, n - 1);
    const ushort* hrow = h2 + (size_t)rowc * DD;
    float po[16];
    #pragma unroll
    for (int q = 0; q < 4; ++q) {
        float4 b4 = *(const float4*)(bout + oc + q * 4);
        po[q * 4 + 0] = b4.x; po[q * 4 + 1] = b4.y;
        po[q * 4 + 2] = b4.z; po[q * 4 + 3] = b4.w;
    }
    for (int k = 0; k < DD; k += 8) {
        uint4 hu = *(const uint4*)(hrow + k);
        float hv[8] = {bflo(hu.x), bfhi(hu.x), bflo(hu.y), bfhi(hu.y),
                       bflo(hu.z), bfhi(hu.z), bflo(hu.w), bfhi(hu.w)};
        #pragma unroll
        for (int j = 0; j < 8; ++j) {
            const float* wrow = &sWo[k + j][oc];
            #pragma unroll
            for (int q = 0; q < 4; ++q) {
                float4 w4 = *(const float4*)(wrow + q * 4);
                po[q * 4 + 0] += hv[j] * w4.x;
                po[q * 4 + 1] += hv[j] * w4.y;
                po[q * 4 + 2] += hv[j] * w4.z;
                po[q * 4 + 3] += hv[j] * w4.w;
            }
        }
    }
    if (row < n) {
        #pragma unroll
        for (int q = 0; q < 4; ++q) {
            float4 o;
            o.x = po[q * 4 + 0]; o.y = po[q * 4 + 1];
            o.z = po[q * 4 + 2]; o.w = po[q * 4 + 3];
            *(float4*)(out + (size_t)row * CC + oc + q * 4) = o;
        }
    }
}

extern "C" void kernel_launch(void* const* d_in, const int* in_sizes, int n_in,
                              void* d_out, int out_size, void* d_ws, size_t ws_size,
                              hipStream_t stream) {
    const float* x    = (const float*)d_in[0];
    const int*   ei   = (const int*)d_in[1];
    const float* W1l  = (const float*)d_in[2];
    const float* b1   = (const float*)d_in[3];
    const float* W1r  = (const float*)d_in[4];
    const float* W2l  = (const float*)d_in[5];
    const float* b2   = (const float*)d_in[6];
    const float* W2r  = (const float*)d_in[7];
    const float* Wout = (const float*)d_in[8];
    const float* bout = (const float*)d_in[9];
    float* out = (float*)d_out;
    const int n = in_sizes[0] / DD;       // 100000
    const int E = in_sizes[1] / 2;        // 1600000
    const size_t NP = (size_t)n * DD;

    const int NB_SCAN = (n + 2047) / 2048;
    const int NBUCK = (n + BKW - 1) / BKW;

    // workspace layout
    int* cnt   = (int*)d_ws;                              // 100352
    int* offs  = cnt + 100352;                            // 100352
    int* bsum  = offs + 100352;                           // 256
    int* bscan = bsum + 256;                              // 256
    int* bcur  = bscan + 256;                             // 256
    int* csr   = bcur + 256;                              // E (pad to even)
    uint2* ebuf = (uint2*)(csr + 1600256);                // E pairs (12.8MB)
    ushort* xh  = (ushort*)ebuf;                          // union region: n*128 bf16 (25.6MB)
    ushort* meanH = xh + NP;                              // n*128 bf16
    ushort* h1h = meanH + NP;                             // n*128 bf16
    ushort* h1l = h1h + NP;                               // n*128 bf16
    ushort* WT1h = h1l + NP;                              // 128*256 each
    ushort* WT1l = WT1h + DD * 256;
    ushort* WT2h = WT1l + DD * 256;
    ushort* WT2l = WT2h + DD * 256;

    hipMemsetAsync(cnt, 0, sizeof(int) * (size_t)n, stream);
    cnt_kernel<<<(E + 255) / 256, 256, 0, stream>>>(ei, cnt, E);
    scan1_kernel<<<NB_SCAN, 256, 0, stream>>>(cnt, offs, bsum, n);
    scan2_kernel<<<1, 64, 0, stream>>>(bsum, bscan, NB_SCAN);
    scan_fix_kernel<<<(n + 255) / 256, 256, 0, stream>>>(offs, bscan, n);
    binit_kernel<<<(NBUCK + 63) / 64, 64, 0, stream>>>(offs, bcur, NBUCK);
    binA_kernel<<<(E + NPB - 1) / NPB, 256, 0, stream>>>(ei, bcur, ebuf, E);
    binB_kernel<<<NBUCK, 256, 0, stream>>>(ebuf, offs, csr, n, E);

    wsplit_kernel<<<DD, 256, 0, stream>>>(W1l, W1r, WT1h, WT1l);
    wsplit_kernel<<<DD, 256, 0, stream>>>(W2l, W2r, WT2h, WT2l);

    // ebuf dead now -> reuse region as xh
    xsplit_kernel<<<(n * DD / 8 + 255) / 256, 256, 0, stream>>>(x, xh, n * DD / 8);

    const int nblk = (n + 63) / 64;
    const int ablk = (n + 3) / 4;

    csr_agg4_kernel<<<ablk, 256, 0, stream>>>(xh, offs, cnt, csr, meanH, n);
    layer_mfma_kernel<false, 1><<<nblk, 256, 0, stream>>>(
        meanH, x, (const ushort*)nullptr, (const ushort*)nullptr,
        WT1h, WT1l, b1, h1h, h1l, n);

    csr_agg4_kernel<<<ablk, 256, 0, stream>>>(h1h, offs, cnt, csr, meanH, n);
    // layer 2 writes h2 (bf16 hi) in place over meanH
    layer_mfma_kernel<true, 2><<<nblk, 256, 0, stream>>>(
        meanH, (const float*)nullptr, h1h, h1l,
        WT2h, WT2l, b2, meanH, (ushort*)nullptr, n);

    proj_kernel<<<nblk, 256, 0, stream>>>(meanH, Wout, bout, out, n);
}

// Round 8
// 364.553 us; speedup vs baseline: 6.4267x; 1.0437x over previous
//
#include <hip/hip_runtime.h>

#define DD 128
#define CC 64
#define BKW 512            // nodes per bucket
#define NPB 4096           // edges per phase-B block

typedef __attribute__((ext_vector_type(8))) short short8v;
typedef __attribute__((ext_vector_type(4))) float f32x4;

static __device__ inline ushort f2bf_rne(float f) {
    unsigned u = __float_as_uint(f);
    unsigned r = (u + 0x7FFFu + ((u >> 16) & 1u)) >> 16;
    return (ushort)r;
}
static __device__ inline float bf2f(ushort h) {
    return __uint_as_float(((unsigned)h) << 16);
}
static __device__ inline float bflo(uint u) {
    return __uint_as_float(u << 16);
}
static __device__ inline float bfhi(uint u) {
    return __uint_as_float(u & 0xffff0000u);
}

// ================= degree count =================
__global__ __launch_bounds__(256) void cnt_kernel(const int* __restrict__ ei,
                                                  int* __restrict__ cnt, int E) {
    int e = blockIdx.x * 256 + threadIdx.x;
    if (e < E) atomicAdd(&cnt[ei[E + e]], 1);
}

// ================= exclusive scan over cnt -> offs =================
__global__ __launch_bounds__(256) void scan1_kernel(const int* __restrict__ cnt,
                                                    int* __restrict__ offs,
                                                    int* __restrict__ bsum, int n) {
    __shared__ int s[256];
    const int t = threadIdx.x;
    const int base = blockIdx.x * 2048 + t * 8;
    int v[8];
    int sum = 0;
    #pragma unroll
    for (int j = 0; j < 8; ++j) {
        int idx = base + j;
        v[j] = (idx < n) ? cnt[idx] : 0;
        sum += v[j];
    }
    s[t] = sum;
    __syncthreads();
    for (int off = 1; off < 256; off <<= 1) {
        int xv = 0;
        if (t >= off) xv = s[t - off];
        __syncthreads();
        if (t >= off) s[t] += xv;
        __syncthreads();
    }
    int run = s[t] - sum;
    #pragma unroll
    for (int j = 0; j < 8; ++j) {
        int idx = base + j;
        if (idx < n) offs[idx] = run;
        run += v[j];
    }
    if (t == 255) bsum[blockIdx.x] = s[255];
}

__global__ void scan2_kernel(const int* __restrict__ bsum,
                             int* __restrict__ bscan, int nb) {
    if (threadIdx.x == 0 && blockIdx.x == 0) {
        int acc = 0;
        for (int i = 0; i < nb; ++i) { bscan[i] = acc; acc += bsum[i]; }
    }
}

__global__ __launch_bounds__(256) void scan_fix_kernel(int* __restrict__ offs,
                                                       const int* __restrict__ bscan,
                                                       int n) {
    int i = blockIdx.x * 256 + threadIdx.x;
    if (i < n) offs[i] += bscan[i >> 11];
}

__global__ void binit_kernel(const int* __restrict__ offs,
                             int* __restrict__ bcur, int nbuck) {
    int b = blockIdx.x * 64 + threadIdx.x;
    if (b < nbuck) bcur[b] = offs[b * BKW];
}

// ================= phase B: bin edges by bucket =================
__global__ __launch_bounds__(256) void binA_kernel(const int* __restrict__ ei,
                                                   int* __restrict__ bcur,
                                                   uint2* __restrict__ ebuf, int E) {
    __shared__ int sRun[256];
    __shared__ int sRel[256];
    __shared__ int sBase[256];
    __shared__ uint2 sPair[NPB];
    __shared__ int sHist[256];
    const int t = threadIdx.x;
    const int e0 = blockIdx.x * NPB;
    const int cntE = min(NPB, E - e0);

    sHist[t] = 0;
    __syncthreads();
    for (int j = t; j < cntE; j += 256) {
        int dst = ei[E + e0 + j];
        atomicAdd(&sHist[dst >> 9], 1);
    }
    __syncthreads();
    int h = sHist[t];
    sRun[t] = h;
    __syncthreads();
    for (int off = 1; off < 256; off <<= 1) {
        int v = 0;
        if (t >= off) v = sRun[t - off];
        __syncthreads();
        if (t >= off) sRun[t] += v;
        __syncthreads();
    }
    int runstart = sRun[t] - h;
    int base = 0;
    if (h > 0) base = atomicAdd(&bcur[t], h);
    sRun[t] = runstart;
    sRel[t] = runstart;
    sBase[t] = base;
    __syncthreads();
    for (int j = t; j < cntE; j += 256) {
        int src = ei[e0 + j];
        int dst = ei[E + e0 + j];
        int b = dst >> 9;
        int slot = atomicAdd(&sRel[b], 1);
        sPair[slot] = make_uint2((unsigned)src, (unsigned)dst);
    }
    __syncthreads();
    for (int s = t; s < cntE; s += 256) {
        uint2 p = sPair[s];
        int b = (int)(p.y >> 9);
        int gpos = sBase[b] + (s - sRun[b]);
        ebuf[gpos] = p;
    }
}

// ================= phase C: per-bucket scatter with LDS cursors =============
__global__ __launch_bounds__(256) void binB_kernel(const uint2* __restrict__ ebuf,
                                                   const int* __restrict__ offs,
                                                   int* __restrict__ csr,
                                                   int n, int E) {
    __shared__ int sOffs[BKW];
    __shared__ int sCur[BKW];
    const int t = threadIdx.x;
    const int node0 = blockIdx.x * BKW;
    const int node1 = min(n, node0 + BKW);
    for (int i = t; i < node1 - node0; i += 256) {
        sOffs[i] = offs[node0 + i];
        sCur[i] = 0;
    }
    __syncthreads();
    const int start = offs[node0];
    const int end = (node1 < n) ? offs[node1] : E;
    for (int j = start + t; j < end; j += 256) {
        uint2 p = ebuf[j];
        int d = (int)p.y - node0;
        int r = atomicAdd(&sCur[d], 1);
        csr[sOffs[d] + r] = (int)p.x;
    }
}

// ================= f32 -> bf16 hi plane =================
__global__ __launch_bounds__(256) void xsplit_kernel(const float* __restrict__ x,
                                                     ushort* __restrict__ xh,
                                                     int total8) {
    int i = blockIdx.x * 256 + threadIdx.x;
    if (i >= total8) return;
    float4 a = ((const float4*)x)[2 * i];
    float4 b = ((const float4*)x)[2 * i + 1];
    ushort r[8] = {f2bf_rne(a.x), f2bf_rne(a.y), f2bf_rne(a.z), f2bf_rne(a.w),
                   f2bf_rne(b.x), f2bf_rne(b.y), f2bf_rne(b.z), f2bf_rne(b.w)};
    uint4 o;
    o.x = (uint)r[0] | ((uint)r[1] << 16);
    o.y = (uint)r[2] | ((uint)r[3] << 16);
    o.z = (uint)r[4] | ((uint)r[5] << 16);
    o.w = (uint)r[6] | ((uint)r[7] << 16);
    ((uint4*)xh)[i] = o;
}

// ====== CSR gather-aggregate: 8 neighbors/loop (2 uint4 loads/lane in flight),
// index loads pipelined one iteration ahead. lane=(sub: slot 0-3, li: dim chunk).
__global__ __launch_bounds__(256) void csr_agg4_kernel(
    const ushort* __restrict__ xh, const int* __restrict__ offs,
    const int* __restrict__ cnt, const int* __restrict__ csr,
    ushort* __restrict__ meanH, int n) {
    int node = blockIdx.x * 4 + (threadIdx.x >> 6);
    if (node >= n) return;
    const int lane = threadIdx.x & 63;
    const int sub = lane >> 4;
    const int li = lane & 15;
    const int start = offs[node];
    const int c = cnt[node];
    float a[8] = {0.f, 0.f, 0.f, 0.f, 0.f, 0.f, 0.f, 0.f};
    const int c8 = c & ~7;
    const int c4 = c & ~3;
    int j = 0;
    if (c8 > 0) {
        int sA = csr[start + sub];
        int sB = csr[start + 4 + sub];
        for (; j < c8; j += 8) {
            int snA = 0, snB = 0;
            if (j + 8 < c8) {
                snA = csr[start + j + 8 + sub];
                snB = csr[start + j + 12 + sub];
            }
            uint4 u0 = *(const uint4*)(xh + (size_t)sA * DD + li * 8);
            uint4 u1 = *(const uint4*)(xh + (size_t)sB * DD + li * 8);
            a[0] += bflo(u0.x); a[1] += bfhi(u0.x);
            a[2] += bflo(u0.y); a[3] += bfhi(u0.y);
            a[4] += bflo(u0.z); a[5] += bfhi(u0.z);
            a[6] += bflo(u0.w); a[7] += bfhi(u0.w);
            a[0] += bflo(u1.x); a[1] += bfhi(u1.x);
            a[2] += bflo(u1.y); a[3] += bfhi(u1.y);
            a[4] += bflo(u1.z); a[5] += bfhi(u1.z);
            a[6] += bflo(u1.w); a[7] += bfhi(u1.w);
            sA = snA; sB = snB;
        }
    }
    if (j < c4) {
        int s = csr[start + j + sub];
        uint4 u = *(const uint4*)(xh + (size_t)s * DD + li * 8);
        a[0] += bflo(u.x); a[1] += bfhi(u.x);
        a[2] += bflo(u.y); a[3] += bfhi(u.y);
        a[4] += bflo(u.z); a[5] += bfhi(u.z);
        a[6] += bflo(u.w); a[7] += bfhi(u.w);
        j += 4;
    }
    if (j + sub < c) {
        int s = csr[start + j + sub];
        uint4 u = *(const uint4*)(xh + (size_t)s * DD + li * 8);
        a[0] += bflo(u.x); a[1] += bfhi(u.x);
        a[2] += bflo(u.y); a[3] += bfhi(u.y);
        a[4] += bflo(u.z); a[5] += bfhi(u.z);
        a[6] += bflo(u.w); a[7] += bfhi(u.w);
    }
    #pragma unroll
    for (int k = 0; k < 8; ++k) {
        a[k] += __shfl_xor(a[k], 16);
        a[k] += __shfl_xor(a[k], 32);
    }
    if (sub == 0) {
        float inv = 1.0f / fmaxf((float)c, 1.0f);
        short8v o;
        #pragma unroll
        for (int k = 0; k < 8; ++k) o[k] = (short)f2bf_rne(a[k] * inv);
        *(short8v*)(meanH + (size_t)node * DD + li * 8) = o;
    }
}

// ====== weight prep: WT_hi/lo[c][k] (k: 0..127 = Wl, 128..255 = Wr) ======
// grid.y selects layer (0/1) via pointer arrays packed by caller.
__global__ __launch_bounds__(256) void wsplit_kernel(
    const float* __restrict__ Wl1, const float* __restrict__ Wr1,
    const float* __restrict__ Wl2, const float* __restrict__ Wr2,
    ushort* __restrict__ WT1h, ushort* __restrict__ WT1l,
    ushort* __restrict__ WT2h, ushort* __restrict__ WT2l) {
    int idx = blockIdx.x * 256 + threadIdx.x;   // c*256 + k
    if (idx >= DD * 256) return;
    int c = idx >> 8, k = idx & 255;
    const float* Wl = blockIdx.y ? Wl2 : Wl1;
    const float* Wr = blockIdx.y ? Wr2 : Wr1;
    ushort* WTh = blockIdx.y ? WT2h : WT1h;
    ushort* WTl = blockIdx.y ? WT2l : WT1l;
    float v = (k < DD) ? Wl[k * DD + c] : Wr[(k - DD) * DD + c];
    ushort h = f2bf_rne(v);
    ushort lo = f2bf_rne(v - bf2f(h));
    WTh[idx] = h;
    WTl[idx] = lo;
}

// ================= MFMA SAGE layer =================
template <bool ROOTPL, int OUTMODE>
__global__ __launch_bounds__(256) void layer_mfma_kernel(
    const ushort* meanH, const float* __restrict__ xf,
    const ushort* __restrict__ rh, const ushort* __restrict__ rl,
    const ushort* __restrict__ WT_hi, const ushort* __restrict__ WT_lo,
    const float* __restrict__ bias,
    ushort* outH, ushort* __restrict__ outL, int n) {
    __shared__ ushort sAh[64][40], sAl[64][40];
    __shared__ ushort sBh[128][40], sBl[128][40];
    const int tid = threadIdx.x;
    const int w = tid >> 6;
    const int l = tid & 63;
    const int row0 = blockIdx.x * 64;

    const int ar  = tid >> 2;
    const int akq = (tid & 3) * 8;
    const int arowg = min(row0 + ar, n - 1);
    const int bc  = tid >> 1;
    const int bkh = (tid & 1) * 16;

    const int arow = w * 16 + (l & 15);
    const int kb   = (l >> 4) * 8;
    const int lcol = l & 15;

    f32x4 acc[8];
    #pragma unroll
    for (int t = 0; t < 8; ++t) acc[t] = (f32x4){0.f, 0.f, 0.f, 0.f};

    // ---- phase A: mean (bf16 plane, lo = 0) ----
    for (int s = 0; s < 4; ++s) {
        const int k0 = s * 32;
        short8v ah_w = *(const short8v*)(meanH + (size_t)arowg * DD + k0 + akq);
        const ushort* bhp = WT_hi + bc * 256 + k0 + bkh;
        const ushort* blp = WT_lo + bc * 256 + k0 + bkh;
        short8v bh0 = *(const short8v*)bhp;
        short8v bh1 = *(const short8v*)(bhp + 8);
        short8v bl0 = *(const short8v*)blp;
        short8v bl1 = *(const short8v*)(blp + 8);

        __syncthreads();
        *(short8v*)&sAh[ar][akq] = ah_w;
        *(short8v*)&sBh[bc][bkh]     = bh0;
        *(short8v*)&sBh[bc][bkh + 8] = bh1;
        *(short8v*)&sBl[bc][bkh]     = bl0;
        *(short8v*)&sBl[bc][bkh + 8] = bl1;
        __syncthreads();

        short8v ah = *(const short8v*)&sAh[arow][kb];
        #pragma unroll
        for (int t = 0; t < 8; ++t) {
            short8v bh = *(const short8v*)&sBh[t * 16 + lcol][kb];
            short8v bl = *(const short8v*)&sBl[t * 16 + lcol][kb];
            acc[t] = __builtin_amdgcn_mfma_f32_16x16x32_bf16(ah, bh, acc[t], 0, 0, 0);
            acc[t] = __builtin_amdgcn_mfma_f32_16x16x32_bf16(ah, bl, acc[t], 0, 0, 0);
        }
    }
    // ---- phase B: root term (hi/lo) ----
    for (int s = 4; s < 8; ++s) {
        const int k0 = s * 32;
        short8v ah_w, al_w;
        if (ROOTPL) {
            ah_w = *(const short8v*)(rh + (size_t)arowg * DD + (k0 - DD) + akq);
            al_w = *(const short8v*)(rl + (size_t)arowg * DD + (k0 - DD) + akq);
        } else {
            const float* Asrc = xf + (size_t)arowg * DD + (k0 - DD);
            float4 v0 = *(const float4*)(Asrc + akq);
            float4 v1 = *(const float4*)(Asrc + akq + 4);
            float vv[8] = {v0.x, v0.y, v0.z, v0.w, v1.x, v1.y, v1.z, v1.w};
            #pragma unroll
            for (int jj = 0; jj < 8; ++jj) {
                ushort hh = f2bf_rne(vv[jj]);
                ah_w[jj] = (short)hh;
                al_w[jj] = (short)f2bf_rne(vv[jj] - bf2f(hh));
            }
        }
        const ushort* bhp = WT_hi + bc * 256 + k0 + bkh;
        const ushort* blp = WT_lo + bc * 256 + k0 + bkh;
        short8v bh0 = *(const short8v*)bhp;
        short8v bh1 = *(const short8v*)(bhp + 8);
        short8v bl0 = *(const short8v*)blp;
        short8v bl1 = *(const short8v*)(blp + 8);

        __syncthreads();
        *(short8v*)&sAh[ar][akq] = ah_w;
        *(short8v*)&sAl[ar][akq] = al_w;
        *(short8v*)&sBh[bc][bkh]     = bh0;
        *(short8v*)&sBh[bc][bkh + 8] = bh1;
        *(short8v*)&sBl[bc][bkh]     = bl0;
        *(short8v*)&sBl[bc][bkh + 8] = bl1;
        __syncthreads();

        short8v ah = *(const short8v*)&sAh[arow][kb];
        short8v al = *(const short8v*)&sAl[arow][kb];
        #pragma unroll
        for (int t = 0; t < 8; ++t) {
            short8v bh = *(const short8v*)&sBh[t * 16 + lcol][kb];
            short8v bl = *(const short8v*)&sBl[t * 16 + lcol][kb];
            acc[t] = __builtin_amdgcn_mfma_f32_16x16x32_bf16(ah, bh, acc[t], 0, 0, 0);
            acc[t] = __builtin_amdgcn_mfma_f32_16x16x32_bf16(al, bh, acc[t], 0, 0, 0);
            acc[t] = __builtin_amdgcn_mfma_f32_16x16x32_bf16(ah, bl, acc[t], 0, 0, 0);
        }
    }

    const int orow0 = row0 + w * 16 + (l >> 4) * 4;
    #pragma unroll
    for (int t = 0; t < 8; ++t) {
        const int col = t * 16 + lcol;
        const float b = bias[col];
        #pragma unroll
        for (int r = 0; r < 4; ++r) {
            int row = orow0 + r;
            if (row < n) {
                float o = fmaxf(acc[t][r] + b, 0.f);
                ushort oh = f2bf_rne(o);
                outH[(size_t)row * DD + col] = oh;
                if (OUTMODE == 1)
                    outL[(size_t)row * DD + col] = f2bf_rne(o - bf2f(oh));
            }
        }
    }
}

// ================= output projection: out = h2h @ Wout + bout =================
__global__ __launch_bounds__(256) void proj_kernel(
    const ushort* __restrict__ h2, const float* __restrict__ Wout,
    const float* __restrict__ bout, float* __restrict__ out, int n) {
    __shared__ float sWo[DD][CC];
    const int tid = threadIdx.x;
    for (int i = tid; i < DD * CC / 4; i += 256) {
        ((float4*)sWo)[i] = ((const float4*)Wout)[i];
    }
    __syncthreads();
    const int prow = tid >> 2;
    const int oc = (tid & 3) * 16;
    const int row = blockIdx.x * 64 + prow;
    const int rowc = min(row, n - 1);
    const ushort* hrow = h2 + (size_t)rowc * DD;
    float po[16];
    #pragma unroll
    for (int q = 0; q < 4; ++q) {
        float4 b4 = *(const float4*)(bout + oc + q * 4);
        po[q * 4 + 0] = b4.x; po[q * 4 + 1] = b4.y;
        po[q * 4 + 2] = b4.z; po[q * 4 + 3] = b4.w;
    }
    for (int k = 0; k < DD; k += 8) {
        uint4 hu = *(const uint4*)(hrow + k);
        float hv[8] = {bflo(hu.x), bfhi(hu.x), bflo(hu.y), bfhi(hu.y),
                       bflo(hu.z), bfhi(hu.z), bflo(hu.w), bfhi(hu.w)};
        #pragma unroll
        for (int j = 0; j < 8; ++j) {
            const float* wrow = &sWo[k + j][oc];
            #pragma unroll
            for (int q = 0; q < 4; ++q) {
                float4 w4 = *(const float4*)(wrow + q * 4);
                po[q * 4 + 0] += hv[j] * w4.x;
                po[q * 4 + 1] += hv[j] * w4.y;
                po[q * 4 + 2] += hv[j] * w4.z;
                po[q * 4 + 3] += hv[j] * w4.w;
            }
        }
    }
    if (row < n) {
        #pragma unroll
        for (int q = 0; q < 4; ++q) {
            float4 o;
            o.x = po[q * 4 + 0]; o.y = po[q * 4 + 1];
            o.z = po[q * 4 + 2]; o.w = po[q * 4 + 3];
            *(float4*)(out + (size_t)row * CC + oc + q * 4) = o;
        }
    }
}

extern "C" void kernel_launch(void* const* d_in, const int* in_sizes, int n_in,
                              void* d_out, int out_size, void* d_ws, size_t ws_size,
                              hipStream_t stream) {
    const float* x    = (const float*)d_in[0];
    const int*   ei   = (const int*)d_in[1];
    const float* W1l  = (const float*)d_in[2];
    const float* b1   = (const float*)d_in[3];
    const float* W1r  = (const float*)d_in[4];
    const float* W2l  = (const float*)d_in[5];
    const float* b2   = (const float*)d_in[6];
    const float* W2r  = (const float*)d_in[7];
    const float* Wout = (const float*)d_in[8];
    const float* bout = (const float*)d_in[9];
    float* out = (float*)d_out;
    const int n = in_sizes[0] / DD;       // 100000
    const int E = in_sizes[1] / 2;        // 1600000
    const size_t NP = (size_t)n * DD;

    const int NB_SCAN = (n + 2047) / 2048;
    const int NBUCK = (n + BKW - 1) / BKW;

    // workspace layout
    int* cnt   = (int*)d_ws;                              // 100352
    int* offs  = cnt + 100352;                            // 100352
    int* bsum  = offs + 100352;                           // 256
    int* bscan = bsum + 256;                              // 256
    int* bcur  = bscan + 256;                             // 256
    int* csr   = bcur + 256;                              // E (pad to even)
    uint2* ebuf = (uint2*)(csr + 1600256);                // E pairs (12.8MB)
    ushort* xh  = (ushort*)ebuf;                          // union: n*128 bf16 (25.6MB)
    ushort* meanH = xh + NP;                              // n*128 bf16
    ushort* h1h = meanH + NP;                             // n*128 bf16
    ushort* h1l = h1h + NP;                               // n*128 bf16
    ushort* WT1h = h1l + NP;                              // 128*256 each
    ushort* WT1l = WT1h + DD * 256;
    ushort* WT2h = WT1l + DD * 256;
    ushort* WT2l = WT2h + DD * 256;

    hipMemsetAsync(cnt, 0, sizeof(int) * (size_t)n, stream);
    cnt_kernel<<<(E + 255) / 256, 256, 0, stream>>>(ei, cnt, E);
    scan1_kernel<<<NB_SCAN, 256, 0, stream>>>(cnt, offs, bsum, n);
    scan2_kernel<<<1, 64, 0, stream>>>(bsum, bscan, NB_SCAN);
    scan_fix_kernel<<<(n + 255) / 256, 256, 0, stream>>>(offs, bscan, n);
    binit_kernel<<<(NBUCK + 63) / 64, 64, 0, stream>>>(offs, bcur, NBUCK);
    binA_kernel<<<(E + NPB - 1) / NPB, 256, 0, stream>>>(ei, bcur, ebuf, E);
    binB_kernel<<<NBUCK, 256, 0, stream>>>(ebuf, offs, csr, n, E);

    dim3 wgrid(DD, 2);
    wsplit_kernel<<<wgrid, 256, 0, stream>>>(W1l, W1r, W2l, W2r,
                                             WT1h, WT1l, WT2h, WT2l);

    // ebuf dead now -> reuse region as xh
    xsplit_kernel<<<(n * DD / 8 + 255) / 256, 256, 0, stream>>>(x, xh, n * DD / 8);

    const int nblk = (n + 63) / 64;
    const int ablk = (n + 3) / 4;

    csr_agg4_kernel<<<ablk, 256, 0, stream>>>(xh, offs, cnt, csr, meanH, n);
    layer_mfma_kernel<false, 1><<<nblk, 256, 0, stream>>>(
        meanH, x, (const ushort*)nullptr, (const ushort*)nullptr,
        WT1h, WT1l, b1, h1h, h1l, n);

    csr_agg4_kernel<<<ablk, 256, 0, stream>>>(h1h, offs, cnt, csr, meanH, n);
    layer_mfma_kernel<true, 2><<<nblk, 256, 0, stream>>>(
        meanH, (const float*)nullptr, h1h, h1l,
        WT2h, WT2l, b2, meanH, (ushort*)nullptr, n);

    proj_kernel<<<nblk, 256, 0, stream>>>(meanH, Wout, bout, out, n);
}

// Round 9
// 308.168 us; speedup vs baseline: 7.6026x; 1.1830x over previous
//
#include <hip/hip_runtime.h>

#define DD 128
#define CC 64
#define BKW 512            // nodes per bucket
#define NPB 4096           // edges per phase-B block

typedef __attribute__((ext_vector_type(8))) short short8v;
typedef __attribute__((ext_vector_type(4))) float f32x4;

static __device__ inline ushort f2bf_rne(float f) {
    unsigned u = __float_as_uint(f);
    unsigned r = (u + 0x7FFFu + ((u >> 16) & 1u)) >> 16;
    return (ushort)r;
}
static __device__ inline float bf2f(ushort h) {
    return __uint_as_float(((unsigned)h) << 16);
}
static __device__ inline float bflo(uint u) {
    return __uint_as_float(u << 16);
}
static __device__ inline float bfhi(uint u) {
    return __uint_as_float(u & 0xffff0000u);
}

// ============ bucket histogram: per-block LDS hist, 256 global atomics ======
__global__ __launch_bounds__(256) void bucket_cnt_kernel(const int* __restrict__ ei,
                                                         int* __restrict__ bcnt, int E) {
    __shared__ int h[256];
    const int t = threadIdx.x;
    h[t] = 0;
    __syncthreads();
    const int base = blockIdx.x * 8192;
    const int end = min(E, base + 8192);
    for (int j = base + t; j < end; j += 256) {
        atomicAdd(&h[ei[E + j] >> 9], 1);
    }
    __syncthreads();
    if (h[t]) atomicAdd(&bcnt[t], h[t]);
}

// ============ bucket scan (256 entries, 1 block) -> boffs[257], bcur ========
__global__ __launch_bounds__(256) void bucket_scan_kernel(const int* __restrict__ bcnt,
                                                          int* __restrict__ boffs,
                                                          int* __restrict__ bcur) {
    __shared__ int s[256];
    const int t = threadIdx.x;
    int v = bcnt[t];
    s[t] = v;
    __syncthreads();
    for (int off = 1; off < 256; off <<= 1) {
        int xv = 0;
        if (t >= off) xv = s[t - off];
        __syncthreads();
        if (t >= off) s[t] += xv;
        __syncthreads();
    }
    int excl = s[t] - v;
    boffs[t] = excl;
    bcur[t] = excl;
    if (t == 255) boffs[256] = s[255];
}

// ================= phase B: bin edges by bucket =================
__global__ __launch_bounds__(256) void binA_kernel(const int* __restrict__ ei,
                                                   int* __restrict__ bcur,
                                                   uint2* __restrict__ ebuf, int E) {
    __shared__ int sRun[256];
    __shared__ int sRel[256];
    __shared__ int sBase[256];
    __shared__ uint2 sPair[NPB];
    __shared__ int sHist[256];
    const int t = threadIdx.x;
    const int e0 = blockIdx.x * NPB;
    const int cntE = min(NPB, E - e0);

    sHist[t] = 0;
    __syncthreads();
    for (int j = t; j < cntE; j += 256) {
        int dst = ei[E + e0 + j];
        atomicAdd(&sHist[dst >> 9], 1);
    }
    __syncthreads();
    int h = sHist[t];
    sRun[t] = h;
    __syncthreads();
    for (int off = 1; off < 256; off <<= 1) {
        int v = 0;
        if (t >= off) v = sRun[t - off];
        __syncthreads();
        if (t >= off) sRun[t] += v;
        __syncthreads();
    }
    int runstart = sRun[t] - h;
    int base = 0;
    if (h > 0) base = atomicAdd(&bcur[t], h);
    sRun[t] = runstart;
    sRel[t] = runstart;
    sBase[t] = base;
    __syncthreads();
    for (int j = t; j < cntE; j += 256) {
        int src = ei[e0 + j];
        int dst = ei[E + e0 + j];
        int b = dst >> 9;
        int slot = atomicAdd(&sRel[b], 1);
        sPair[slot] = make_uint2((unsigned)src, (unsigned)dst);
    }
    __syncthreads();
    for (int s = t; s < cntE; s += 256) {
        uint2 p = sPair[s];
        int b = (int)(p.y >> 9);
        int gpos = sBase[b] + (s - sRun[b]);
        ebuf[gpos] = p;
    }
}

// ====== phase C: per-bucket: derive per-node cnt/offs in LDS, then scatter ====
__global__ __launch_bounds__(256) void binB2_kernel(const uint2* __restrict__ ebuf,
                                                    const int* __restrict__ boffs,
                                                    int* __restrict__ offs,
                                                    int* __restrict__ cnt,
                                                    int* __restrict__ csr, int n) {
    __shared__ int sCnt[BKW];
    __shared__ int sOffs[BKW];
    __shared__ int sScan[256];
    const int t = threadIdx.x;
    const int node0 = blockIdx.x * BKW;
    const int start = boffs[blockIdx.x];
    const int end = boffs[blockIdx.x + 1];

    sCnt[t] = 0; sCnt[t + 256] = 0;
    __syncthreads();
    for (int j = start + t; j < end; j += 256) {
        int d = (int)ebuf[j].y - node0;
        atomicAdd(&sCnt[d], 1);
    }
    __syncthreads();
    // exclusive scan over 512 (2 per thread)
    int v0 = sCnt[2 * t], v1 = sCnt[2 * t + 1];
    int sum = v0 + v1;
    sScan[t] = sum;
    __syncthreads();
    for (int off = 1; off < 256; off <<= 1) {
        int xv = 0;
        if (t >= off) xv = sScan[t - off];
        __syncthreads();
        if (t >= off) sScan[t] += xv;
        __syncthreads();
    }
    int excl = sScan[t] - sum;
    sOffs[2 * t] = start + excl;
    sOffs[2 * t + 1] = start + excl + v0;
    __syncthreads();
    // write per-node offs/cnt (coalesced)
    for (int i = t; i < BKW; i += 256) {
        int node = node0 + i;
        if (node < n) { offs[node] = sOffs[i]; cnt[node] = sCnt[i]; }
    }
    __syncthreads();
    sCnt[t] = 0; sCnt[t + 256] = 0;     // reuse as cursors
    __syncthreads();
    for (int j = start + t; j < end; j += 256) {
        uint2 p = ebuf[j];
        int d = (int)p.y - node0;
        int r = atomicAdd(&sCnt[d], 1);
        csr[sOffs[d] + r] = (int)p.x;
    }
}

// ================= f32 -> bf16 hi plane =================
__global__ __launch_bounds__(256) void xsplit_kernel(const float* __restrict__ x,
                                                     ushort* __restrict__ xh,
                                                     int total8) {
    int i = blockIdx.x * 256 + threadIdx.x;
    if (i >= total8) return;
    float4 a = ((const float4*)x)[2 * i];
    float4 b = ((const float4*)x)[2 * i + 1];
    ushort r[8] = {f2bf_rne(a.x), f2bf_rne(a.y), f2bf_rne(a.z), f2bf_rne(a.w),
                   f2bf_rne(b.x), f2bf_rne(b.y), f2bf_rne(b.z), f2bf_rne(b.w)};
    uint4 o;
    o.x = (uint)r[0] | ((uint)r[1] << 16);
    o.y = (uint)r[2] | ((uint)r[3] << 16);
    o.z = (uint)r[4] | ((uint)r[5] << 16);
    o.w = (uint)r[6] | ((uint)r[7] << 16);
    ((uint4*)xh)[i] = o;
}

// ====== CSR gather-aggregate: up to 16 neighbors in flight per wave =========
__global__ __launch_bounds__(256) void csr_agg4_kernel(
    const ushort* __restrict__ xh, const int* __restrict__ offs,
    const int* __restrict__ cnt, const int* __restrict__ csr,
    ushort* __restrict__ meanH, int n) {
    int node = blockIdx.x * 4 + (threadIdx.x >> 6);
    if (node >= n) return;
    const int lane = threadIdx.x & 63;
    const int sub = lane >> 4;
    const int li = lane & 15;
    const int start = offs[node];
    const int c = cnt[node];
    float a[8] = {0.f, 0.f, 0.f, 0.f, 0.f, 0.f, 0.f, 0.f};
    float aa[8] = {0.f, 0.f, 0.f, 0.f, 0.f, 0.f, 0.f, 0.f};
    const int c16 = c & ~15;
    int j = 0;
    if (c16 > 0) {
        int s0 = csr[start + sub];
        int s1 = csr[start + 4 + sub];
        int s2 = csr[start + 8 + sub];
        int s3 = csr[start + 12 + sub];
        for (; j < c16; j += 16) {
            int t0 = 0, t1 = 0, t2 = 0, t3 = 0;
            if (j + 16 < c16) {
                t0 = csr[start + j + 16 + sub];
                t1 = csr[start + j + 20 + sub];
                t2 = csr[start + j + 24 + sub];
                t3 = csr[start + j + 28 + sub];
            }
            uint4 u0 = *(const uint4*)(xh + (size_t)s0 * DD + li * 8);
            uint4 u1 = *(const uint4*)(xh + (size_t)s1 * DD + li * 8);
            uint4 u2 = *(const uint4*)(xh + (size_t)s2 * DD + li * 8);
            uint4 u3 = *(const uint4*)(xh + (size_t)s3 * DD + li * 8);
            a[0] += bflo(u0.x); a[1] += bfhi(u0.x);
            a[2] += bflo(u0.y); a[3] += bfhi(u0.y);
            a[4] += bflo(u0.z); a[5] += bfhi(u0.z);
            a[6] += bflo(u0.w); a[7] += bfhi(u0.w);
            a[0] += bflo(u1.x); a[1] += bfhi(u1.x);
            a[2] += bflo(u1.y); a[3] += bfhi(u1.y);
            a[4] += bflo(u1.z); a[5] += bfhi(u1.z);
            a[6] += bflo(u1.w); a[7] += bfhi(u1.w);
            aa[0] += bflo(u2.x); aa[1] += bfhi(u2.x);
            aa[2] += bflo(u2.y); aa[3] += bfhi(u2.y);
            aa[4] += bflo(u2.z); aa[5] += bfhi(u2.z);
            aa[6] += bflo(u2.w); aa[7] += bfhi(u2.w);
            aa[0] += bflo(u3.x); aa[1] += bfhi(u3.x);
            aa[2] += bflo(u3.y); aa[3] += bfhi(u3.y);
            aa[4] += bflo(u3.z); aa[5] += bfhi(u3.z);
            aa[6] += bflo(u3.w); aa[7] += bfhi(u3.w);
            s0 = t0; s1 = t1; s2 = t2; s3 = t3;
        }
    }
    if (c - j >= 8) {
        int s0 = csr[start + j + sub];
        int s1 = csr[start + j + 4 + sub];
        uint4 u0 = *(const uint4*)(xh + (size_t)s0 * DD + li * 8);
        uint4 u1 = *(const uint4*)(xh + (size_t)s1 * DD + li * 8);
        a[0] += bflo(u0.x); a[1] += bfhi(u0.x);
        a[2] += bflo(u0.y); a[3] += bfhi(u0.y);
        a[4] += bflo(u0.z); a[5] += bfhi(u0.z);
        a[6] += bflo(u0.w); a[7] += bfhi(u0.w);
        aa[0] += bflo(u1.x); aa[1] += bfhi(u1.x);
        aa[2] += bflo(u1.y); aa[3] += bfhi(u1.y);
        aa[4] += bflo(u1.z); aa[5] += bfhi(u1.z);
        aa[6] += bflo(u1.w); aa[7] += bfhi(u1.w);
        j += 8;
    }
    if (c - j >= 4) {
        int s = csr[start + j + sub];
        uint4 u = *(const uint4*)(xh + (size_t)s * DD + li * 8);
        a[0] += bflo(u.x); a[1] += bfhi(u.x);
        a[2] += bflo(u.y); a[3] += bfhi(u.y);
        a[4] += bflo(u.z); a[5] += bfhi(u.z);
        a[6] += bflo(u.w); a[7] += bfhi(u.w);
        j += 4;
    }
    if (j + sub < c) {
        int s = csr[start + j + sub];
        uint4 u = *(const uint4*)(xh + (size_t)s * DD + li * 8);
        a[0] += bflo(u.x); a[1] += bfhi(u.x);
        a[2] += bflo(u.y); a[3] += bfhi(u.y);
        a[4] += bflo(u.z); a[5] += bfhi(u.z);
        a[6] += bflo(u.w); a[7] += bfhi(u.w);
    }
    #pragma unroll
    for (int k = 0; k < 8; ++k) {
        float v = a[k] + aa[k];
        v += __shfl_xor(v, 16);
        v += __shfl_xor(v, 32);
        a[k] = v;
    }
    if (sub == 0) {
        float inv = 1.0f / fmaxf((float)c, 1.0f);
        short8v o;
        #pragma unroll
        for (int k = 0; k < 8; ++k) o[k] = (short)f2bf_rne(a[k] * inv);
        *(short8v*)(meanH + (size_t)node * DD + li * 8) = o;
    }
}

// ====== weight prep: WT_hi/lo[c][k] (k: 0..127 = Wl, 128..255 = Wr) ======
__global__ __launch_bounds__(256) void wsplit_kernel(
    const float* __restrict__ Wl1, const float* __restrict__ Wr1,
    const float* __restrict__ Wl2, const float* __restrict__ Wr2,
    ushort* __restrict__ WT1h, ushort* __restrict__ WT1l,
    ushort* __restrict__ WT2h, ushort* __restrict__ WT2l) {
    int idx = blockIdx.x * 256 + threadIdx.x;   // c*256 + k
    if (idx >= DD * 256) return;
    int c = idx >> 8, k = idx & 255;
    const float* Wl = blockIdx.y ? Wl2 : Wl1;
    const float* Wr = blockIdx.y ? Wr2 : Wr1;
    ushort* WTh = blockIdx.y ? WT2h : WT1h;
    ushort* WTl = blockIdx.y ? WT2l : WT1l;
    float v = (k < DD) ? Wl[k * DD + c] : Wr[(k - DD) * DD + c];
    ushort h = f2bf_rne(v);
    ushort lo = f2bf_rne(v - bf2f(h));
    WTh[idx] = h;
    WTl[idx] = lo;
}

// ================= MFMA SAGE layer =================
template <bool ROOTPL, int OUTMODE>
__global__ __launch_bounds__(256) void layer_mfma_kernel(
    const ushort* meanH, const float* __restrict__ xf,
    const ushort* __restrict__ rh, const ushort* __restrict__ rl,
    const ushort* __restrict__ WT_hi, const ushort* __restrict__ WT_lo,
    const float* __restrict__ bias,
    ushort* outH, ushort* __restrict__ outL, int n) {
    __shared__ ushort sAh[64][40], sAl[64][40];
    __shared__ ushort sBh[128][40], sBl[128][40];
    const int tid = threadIdx.x;
    const int w = tid >> 6;
    const int l = tid & 63;
    const int row0 = blockIdx.x * 64;

    const int ar  = tid >> 2;
    const int akq = (tid & 3) * 8;
    const int arowg = min(row0 + ar, n - 1);
    const int bc  = tid >> 1;
    const int bkh = (tid & 1) * 16;

    const int arow = w * 16 + (l & 15);
    const int kb   = (l >> 4) * 8;
    const int lcol = l & 15;

    f32x4 acc[8];
    #pragma unroll
    for (int t = 0; t < 8; ++t) acc[t] = (f32x4){0.f, 0.f, 0.f, 0.f};

    // ---- phase A: mean (bf16 plane, lo = 0) ----
    for (int s = 0; s < 4; ++s) {
        const int k0 = s * 32;
        short8v ah_w = *(const short8v*)(meanH + (size_t)arowg * DD + k0 + akq);
        const ushort* bhp = WT_hi + bc * 256 + k0 + bkh;
        const ushort* blp = WT_lo + bc * 256 + k0 + bkh;
        short8v bh0 = *(const short8v*)bhp;
        short8v bh1 = *(const short8v*)(bhp + 8);
        short8v bl0 = *(const short8v*)blp;
        short8v bl1 = *(const short8v*)(blp + 8);

        __syncthreads();
        *(short8v*)&sAh[ar][akq] = ah_w;
        *(short8v*)&sBh[bc][bkh]     = bh0;
        *(short8v*)&sBh[bc][bkh + 8] = bh1;
        *(short8v*)&sBl[bc][bkh]     = bl0;
        *(short8v*)&sBl[bc][bkh + 8] = bl1;
        __syncthreads();

        short8v ah = *(const short8v*)&sAh[arow][kb];
        #pragma unroll
        for (int t = 0; t < 8; ++t) {
            short8v bh = *(const short8v*)&sBh[t * 16 + lcol][kb];
            short8v bl = *(const short8v*)&sBl[t * 16 + lcol][kb];
            acc[t] = __builtin_amdgcn_mfma_f32_16x16x32_bf16(ah, bh, acc[t], 0, 0, 0);
            acc[t] = __builtin_amdgcn_mfma_f32_16x16x32_bf16(ah, bl, acc[t], 0, 0, 0);
        }
    }
    // ---- phase B: root term (hi/lo) ----
    for (int s = 4; s < 8; ++s) {
        const int k0 = s * 32;
        short8v ah_w, al_w;
        if (ROOTPL) {
            ah_w = *(const short8v*)(rh + (size_t)arowg * DD + (k0 - DD) + akq);
            al_w = *(const short8v*)(rl + (size_t)arowg * DD + (k0 - DD) + akq);
        } else {
            const float* Asrc = xf + (size_t)arowg * DD + (k0 - DD);
            float4 v0 = *(const float4*)(Asrc + akq);
            float4 v1 = *(const float4*)(Asrc + akq + 4);
            float vv[8] = {v0.x, v0.y, v0.z, v0.w, v1.x, v1.y, v1.z, v1.w};
            #pragma unroll
            for (int jj = 0; jj < 8; ++jj) {
                ushort hh = f2bf_rne(vv[jj]);
                ah_w[jj] = (short)hh;
                al_w[jj] = (short)f2bf_rne(vv[jj] - bf2f(hh));
            }
        }
        const ushort* bhp = WT_hi + bc * 256 + k0 + bkh;
        const ushort* blp = WT_lo + bc * 256 + k0 + bkh;
        short8v bh0 = *(const short8v*)bhp;
        short8v bh1 = *(const short8v*)(bhp + 8);
        short8v bl0 = *(const short8v*)blp;
        short8v bl1 = *(const short8v*)(blp + 8);

        __syncthreads();
        *(short8v*)&sAh[ar][akq] = ah_w;
        *(short8v*)&sAl[ar][akq] = al_w;
        *(short8v*)&sBh[bc][bkh]     = bh0;
        *(short8v*)&sBh[bc][bkh + 8] = bh1;
        *(short8v*)&sBl[bc][bkh]     = bl0;
        *(short8v*)&sBl[bc][bkh + 8] = bl1;
        __syncthreads();

        short8v ah = *(const short8v*)&sAh[arow][kb];
        short8v al = *(const short8v*)&sAl[arow][kb];
        #pragma unroll
        for (int t = 0; t < 8; ++t) {
            short8v bh = *(const short8v*)&sBh[t * 16 + lcol][kb];
            short8v bl = *(const short8v*)&sBl[t * 16 + lcol][kb];
            acc[t] = __builtin_amdgcn_mfma_f32_16x16x32_bf16(ah, bh, acc[t], 0, 0, 0);
            acc[t] = __builtin_amdgcn_mfma_f32_16x16x32_bf16(al, bh, acc[t], 0, 0, 0);
            acc[t] = __builtin_amdgcn_mfma_f32_16x16x32_bf16(ah, bl, acc[t], 0, 0, 0);
        }
    }

    const int orow0 = row0 + w * 16 + (l >> 4) * 4;
    #pragma unroll
    for (int t = 0; t < 8; ++t) {
        const int col = t * 16 + lcol;
        const float b = bias[col];
        #pragma unroll
        for (int r = 0; r < 4; ++r) {
            int row = orow0 + r;
            if (row < n) {
                float o = fmaxf(acc[t][r] + b, 0.f);
                ushort oh = f2bf_rne(o);
                outH[(size_t)row * DD + col] = oh;
                if (OUTMODE == 1)
                    outL[(size_t)row * DD + col] = f2bf_rne(o - bf2f(oh));
            }
        }
    }
}

// ================= output projection: out = h2h @ Wout + bout =================
__global__ __launch_bounds__(256) void proj_kernel(
    const ushort* __restrict__ h2, const float* __restrict__ Wout,
    const float* __restrict__ bout, float* __restrict__ out, int n) {
    __shared__ float sWo[DD][CC];
    const int tid = threadIdx.x;
    for (int i = tid; i < DD * CC / 4; i += 256) {
        ((float4*)sWo)[i] = ((const float4*)Wout)[i];
    }
    __syncthreads();
    const int prow = tid >> 2;
    const int oc = (tid & 3) * 16;
    const int row = blockIdx.x * 64 + prow;
    const int rowc = min(row, n - 1);
    const ushort* hrow = h2 + (size_t)rowc * DD;
    float po[16];
    #pragma unroll
    for (int q = 0; q < 4; ++q) {
        float4 b4 = *(const float4*)(bout + oc + q * 4);
        po[q * 4 + 0] = b4.x; po[q * 4 + 1] = b4.y;
        po[q * 4 + 2] = b4.z; po[q * 4 + 3] = b4.w;
    }
    for (int k = 0; k < DD; k += 8) {
        uint4 hu = *(const uint4*)(hrow + k);
        float hv[8] = {bflo(hu.x), bfhi(hu.x), bflo(hu.y), bfhi(hu.y),
                       bflo(hu.z), bfhi(hu.z), bflo(hu.w), bfhi(hu.w)};
        #pragma unroll
        for (int j = 0; j < 8; ++j) {
            const float* wrow = &sWo[k + j][oc];
            #pragma unroll
            for (int q = 0; q < 4; ++q) {
                float4 w4 = *(const float4*)(wrow + q * 4);
                po[q * 4 + 0] += hv[j] * w4.x;
                po[q * 4 + 1] += hv[j] * w4.y;
                po[q * 4 + 2] += hv[j] * w4.z;
                po[q * 4 + 3] += hv[j] * w4.w;
            }
        }
    }
    if (row < n) {
        #pragma unroll
        for (int q = 0; q < 4; ++q) {
            float4 o;
            o.x = po[q * 4 + 0]; o.y = po[q * 4 + 1];
            o.z = po[q * 4 + 2]; o.w = po[q * 4 + 3];
            *(float4*)(out + (size_t)row * CC + oc + q * 4) = o;
        }
    }
}

extern "C" void kernel_launch(void* const* d_in, const int* in_sizes, int n_in,
                              void* d_out, int out_size, void* d_ws, size_t ws_size,
                              hipStream_t stream) {
    const float* x    = (const float*)d_in[0];
    const int*   ei   = (const int*)d_in[1];
    const float* W1l  = (const float*)d_in[2];
    const float* b1   = (const float*)d_in[3];
    const float* W1r  = (const float*)d_in[4];
    const float* W2l  = (const float*)d_in[5];
    const float* b2   = (const float*)d_in[6];
    const float* W2r  = (const float*)d_in[7];
    const float* Wout = (const float*)d_in[8];
    const float* bout = (const float*)d_in[9];
    float* out = (float*)d_out;
    const int n = in_sizes[0] / DD;       // 100000
    const int E = in_sizes[1] / 2;        // 1600000
    const size_t NP = (size_t)n * DD;

    const int NBUCK = (n + BKW - 1) / BKW;

    // workspace layout
    int* cnt   = (int*)d_ws;                              // 100352
    int* offs  = cnt + 100352;                            // 100352
    int* bcnt  = offs + 100352;                           // 256
    int* boffs = bcnt + 256;                              // 257 (pad 512)
    int* bcur  = boffs + 512;                             // 256
    int* csr   = bcur + 256;                              // E (pad)
    uint2* ebuf = (uint2*)(csr + 1600256);                // E pairs (12.8MB)
    ushort* xh  = (ushort*)ebuf;                          // union: n*128 bf16 (25.6MB)
    ushort* meanH = xh + NP;                              // n*128 bf16
    ushort* h1h = meanH + NP;                             // n*128 bf16
    ushort* h1l = h1h + NP;                               // n*128 bf16
    ushort* WT1h = h1l + NP;                              // 128*256 each
    ushort* WT1l = WT1h + DD * 256;
    ushort* WT2h = WT1l + DD * 256;
    ushort* WT2l = WT2h + DD * 256;

    hipMemsetAsync(bcnt, 0, sizeof(int) * 256, stream);
    bucket_cnt_kernel<<<(E + 8191) / 8192, 256, 0, stream>>>(ei, bcnt, E);
    bucket_scan_kernel<<<1, 256, 0, stream>>>(bcnt, boffs, bcur);
    binA_kernel<<<(E + NPB - 1) / NPB, 256, 0, stream>>>(ei, bcur, ebuf, E);
    binB2_kernel<<<NBUCK, 256, 0, stream>>>(ebuf, boffs, offs, cnt, csr, n);

    dim3 wgrid(DD, 2);
    wsplit_kernel<<<wgrid, 256, 0, stream>>>(W1l, W1r, W2l, W2r,
                                             WT1h, WT1l, WT2h, WT2l);

    // ebuf dead now -> reuse region as xh
    xsplit_kernel<<<(n * DD / 8 + 255) / 256, 256, 0, stream>>>(x, xh, n * DD / 8);

    const int nblk = (n + 63) / 64;
    const int ablk = (n + 3) / 4;

    csr_agg4_kernel<<<ablk, 256, 0, stream>>>(xh, offs, cnt, csr, meanH, n);
    layer_mfma_kernel<false, 1><<<nblk, 256, 0, stream>>>(
        meanH, x, (const ushort*)nullptr, (const ushort*)nullptr,
        WT1h, WT1l, b1, h1h, h1l, n);

    csr_agg4_kernel<<<ablk, 256, 0, stream>>>(h1h, offs, cnt, csr, meanH, n);
    layer_mfma_kernel<true, 2><<<nblk, 256, 0, stream>>>(
        meanH, (const float*)nullptr, h1h, h1l,
        WT2h, WT2l, b2, meanH, (ushort*)nullptr, n);

    proj_kernel<<<nblk, 256, 0, stream>>>(meanH, Wout, bout, out, n);
}

// Round 10
// 282.437 us; speedup vs baseline: 8.2952x; 1.0911x over previous
//
#include <hip/hip_runtime.h>

#define DD 128
#define CC 64
#define BKW 512            // nodes per bucket
#define NPB 4096           // edges per phase-B block

typedef __attribute__((ext_vector_type(8))) short short8v;
typedef __attribute__((ext_vector_type(4))) float f32x4;
typedef __attribute__((ext_vector_type(2))) float f32x2;

static __device__ inline ushort f2bf_rne(float f) {
    unsigned u = __float_as_uint(f);
    unsigned r = (u + 0x7FFFu + ((u >> 16) & 1u)) >> 16;
    return (ushort)r;
}
static __device__ inline float bf2f(ushort h) {
    return __uint_as_float(((unsigned)h) << 16);
}
static __device__ inline float bflo(uint u) {
    return __uint_as_float(u << 16);
}
static __device__ inline float bfhi(uint u) {
    return __uint_as_float(u & 0xffff0000u);
}

// ============ bucket histogram: per-block LDS hist, 256 global atomics ======
__global__ __launch_bounds__(256) void bucket_cnt_kernel(const int* __restrict__ ei,
                                                         int* __restrict__ bcnt, int E) {
    __shared__ int h[256];
    const int t = threadIdx.x;
    h[t] = 0;
    __syncthreads();
    const int base = blockIdx.x * 8192;
    const int end = min(E, base + 8192);
    for (int j = base + t; j < end; j += 256) {
        atomicAdd(&h[ei[E + j] >> 9], 1);
    }
    __syncthreads();
    if (h[t]) atomicAdd(&bcnt[t], h[t]);
}

// ============ bucket scan (256 entries, 1 block) -> boffs[257], bcur ========
__global__ __launch_bounds__(256) void bucket_scan_kernel(const int* __restrict__ bcnt,
                                                          int* __restrict__ boffs,
                                                          int* __restrict__ bcur) {
    __shared__ int s[256];
    const int t = threadIdx.x;
    int v = bcnt[t];
    s[t] = v;
    __syncthreads();
    for (int off = 1; off < 256; off <<= 1) {
        int xv = 0;
        if (t >= off) xv = s[t - off];
        __syncthreads();
        if (t >= off) s[t] += xv;
        __syncthreads();
    }
    int excl = s[t] - v;
    boffs[t] = excl;
    bcur[t] = excl;
    if (t == 255) boffs[256] = s[255];
}

// ================= phase B: bin edges by bucket =================
__global__ __launch_bounds__(256) void binA_kernel(const int* __restrict__ ei,
                                                   int* __restrict__ bcur,
                                                   uint2* __restrict__ ebuf, int E) {
    __shared__ int sRun[256];
    __shared__ int sRel[256];
    __shared__ int sBase[256];
    __shared__ uint2 sPair[NPB];
    __shared__ int sHist[256];
    const int t = threadIdx.x;
    const int e0 = blockIdx.x * NPB;
    const int cntE = min(NPB, E - e0);

    sHist[t] = 0;
    __syncthreads();
    for (int j = t; j < cntE; j += 256) {
        int dst = ei[E + e0 + j];
        atomicAdd(&sHist[dst >> 9], 1);
    }
    __syncthreads();
    int h = sHist[t];
    sRun[t] = h;
    __syncthreads();
    for (int off = 1; off < 256; off <<= 1) {
        int v = 0;
        if (t >= off) v = sRun[t - off];
        __syncthreads();
        if (t >= off) sRun[t] += v;
        __syncthreads();
    }
    int runstart = sRun[t] - h;
    int base = 0;
    if (h > 0) base = atomicAdd(&bcur[t], h);
    sRun[t] = runstart;
    sRel[t] = runstart;
    sBase[t] = base;
    __syncthreads();
    for (int j = t; j < cntE; j += 256) {
        int src = ei[e0 + j];
        int dst = ei[E + e0 + j];
        int b = dst >> 9;
        int slot = atomicAdd(&sRel[b], 1);
        sPair[slot] = make_uint2((unsigned)src, (unsigned)dst);
    }
    __syncthreads();
    for (int s = t; s < cntE; s += 256) {
        uint2 p = sPair[s];
        int b = (int)(p.y >> 9);
        int gpos = sBase[b] + (s - sRun[b]);
        ebuf[gpos] = p;
    }
}

// ====== phase C: per-bucket: derive per-node cnt/offs in LDS, then scatter ====
__global__ __launch_bounds__(256) void binB2_kernel(const uint2* __restrict__ ebuf,
                                                    const int* __restrict__ boffs,
                                                    int* __restrict__ offs,
                                                    int* __restrict__ cnt,
                                                    int* __restrict__ csr, int n) {
    __shared__ int sCnt[BKW];
    __shared__ int sOffs[BKW];
    __shared__ int sScan[256];
    const int t = threadIdx.x;
    const int node0 = blockIdx.x * BKW;
    const int start = boffs[blockIdx.x];
    const int end = boffs[blockIdx.x + 1];

    sCnt[t] = 0; sCnt[t + 256] = 0;
    __syncthreads();
    for (int j = start + t; j < end; j += 256) {
        int d = (int)ebuf[j].y - node0;
        atomicAdd(&sCnt[d], 1);
    }
    __syncthreads();
    int v0 = sCnt[2 * t], v1 = sCnt[2 * t + 1];
    int sum = v0 + v1;
    sScan[t] = sum;
    __syncthreads();
    for (int off = 1; off < 256; off <<= 1) {
        int xv = 0;
        if (t >= off) xv = sScan[t - off];
        __syncthreads();
        if (t >= off) sScan[t] += xv;
        __syncthreads();
    }
    int excl = sScan[t] - sum;
    sOffs[2 * t] = start + excl;
    sOffs[2 * t + 1] = start + excl + v0;
    __syncthreads();
    for (int i = t; i < BKW; i += 256) {
        int node = node0 + i;
        if (node < n) { offs[node] = sOffs[i]; cnt[node] = sCnt[i]; }
    }
    __syncthreads();
    sCnt[t] = 0; sCnt[t + 256] = 0;
    __syncthreads();
    for (int j = start + t; j < end; j += 256) {
        uint2 p = ebuf[j];
        int d = (int)p.y - node0;
        int r = atomicAdd(&sCnt[d], 1);
        csr[sOffs[d] + r] = (int)p.x;
    }
}

// ================= f32 -> bf16 hi plane =================
__global__ __launch_bounds__(256) void xsplit_kernel(const float* __restrict__ x,
                                                     ushort* __restrict__ xh,
                                                     int total8) {
    int i = blockIdx.x * 256 + threadIdx.x;
    if (i >= total8) return;
    float4 a = ((const float4*)x)[2 * i];
    float4 b = ((const float4*)x)[2 * i + 1];
    ushort r[8] = {f2bf_rne(a.x), f2bf_rne(a.y), f2bf_rne(a.z), f2bf_rne(a.w),
                   f2bf_rne(b.x), f2bf_rne(b.y), f2bf_rne(b.z), f2bf_rne(b.w)};
    uint4 o;
    o.x = (uint)r[0] | ((uint)r[1] << 16);
    o.y = (uint)r[2] | ((uint)r[3] << 16);
    o.z = (uint)r[4] | ((uint)r[5] << 16);
    o.w = (uint)r[6] | ((uint)r[7] << 16);
    ((uint4*)xh)[i] = o;
}

// ====== CSR gather-aggregate: up to 16 neighbors in flight, f32x2 accum =====
__global__ __launch_bounds__(256) void csr_agg4_kernel(
    const ushort* __restrict__ xh, const int* __restrict__ offs,
    const int* __restrict__ cnt, const int* __restrict__ csr,
    ushort* __restrict__ meanH, int n) {
    int node = blockIdx.x * 4 + (threadIdx.x >> 6);
    if (node >= n) return;
    const int lane = threadIdx.x & 63;
    const int sub = lane >> 4;
    const int li = lane & 15;
    const int start = offs[node];
    const int c = cnt[node];
    f32x2 a[4], aa[4];
    #pragma unroll
    for (int k = 0; k < 4; ++k) { a[k] = (f32x2){0.f, 0.f}; aa[k] = (f32x2){0.f, 0.f}; }
    #define ACC4(A, U) \
        A[0] += (f32x2){bflo(U.x), bfhi(U.x)}; \
        A[1] += (f32x2){bflo(U.y), bfhi(U.y)}; \
        A[2] += (f32x2){bflo(U.z), bfhi(U.z)}; \
        A[3] += (f32x2){bflo(U.w), bfhi(U.w)};
    const int c16 = c & ~15;
    int j = 0;
    if (c16 > 0) {
        int s0 = csr[start + sub];
        int s1 = csr[start + 4 + sub];
        int s2 = csr[start + 8 + sub];
        int s3 = csr[start + 12 + sub];
        for (; j < c16; j += 16) {
            int t0 = 0, t1 = 0, t2 = 0, t3 = 0;
            if (j + 16 < c16) {
                t0 = csr[start + j + 16 + sub];
                t1 = csr[start + j + 20 + sub];
                t2 = csr[start + j + 24 + sub];
                t3 = csr[start + j + 28 + sub];
            }
            uint4 u0 = *(const uint4*)(xh + (size_t)s0 * DD + li * 8);
            uint4 u1 = *(const uint4*)(xh + (size_t)s1 * DD + li * 8);
            uint4 u2 = *(const uint4*)(xh + (size_t)s2 * DD + li * 8);
            uint4 u3 = *(const uint4*)(xh + (size_t)s3 * DD + li * 8);
            ACC4(a, u0); ACC4(a, u1); ACC4(aa, u2); ACC4(aa, u3);
            s0 = t0; s1 = t1; s2 = t2; s3 = t3;
        }
    }
    if (c - j >= 8) {
        int s0 = csr[start + j + sub];
        int s1 = csr[start + j + 4 + sub];
        uint4 u0 = *(const uint4*)(xh + (size_t)s0 * DD + li * 8);
        uint4 u1 = *(const uint4*)(xh + (size_t)s1 * DD + li * 8);
        ACC4(a, u0); ACC4(aa, u1);
        j += 8;
    }
    if (c - j >= 4) {
        int s = csr[start + j + sub];
        uint4 u = *(const uint4*)(xh + (size_t)s * DD + li * 8);
        ACC4(a, u);
        j += 4;
    }
    if (j + sub < c) {
        int s = csr[start + j + sub];
        uint4 u = *(const uint4*)(xh + (size_t)s * DD + li * 8);
        ACC4(aa, u);
    }
    #undef ACC4
    float res[8];
    #pragma unroll
    for (int k = 0; k < 4; ++k) {
        f32x2 v = a[k] + aa[k];
        float e0 = v.x; e0 += __shfl_xor(e0, 16); e0 += __shfl_xor(e0, 32);
        float e1 = v.y; e1 += __shfl_xor(e1, 16); e1 += __shfl_xor(e1, 32);
        res[2 * k] = e0; res[2 * k + 1] = e1;
    }
    if (sub == 0) {
        float inv = 1.0f / fmaxf((float)c, 1.0f);
        short8v o;
        #pragma unroll
        for (int k = 0; k < 8; ++k) o[k] = (short)f2bf_rne(res[k] * inv);
        *(short8v*)(meanH + (size_t)node * DD + li * 8) = o;
    }
}

// ====== weight prep: WT_hi/lo[c][k] (k: 0..127 = Wl, 128..255 = Wr) ======
__global__ __launch_bounds__(256) void wsplit_kernel(
    const float* __restrict__ Wl1, const float* __restrict__ Wr1,
    const float* __restrict__ Wl2, const float* __restrict__ Wr2,
    ushort* __restrict__ WT1h, ushort* __restrict__ WT1l,
    ushort* __restrict__ WT2h, ushort* __restrict__ WT2l) {
    int idx = blockIdx.x * 256 + threadIdx.x;   // c*256 + k
    if (idx >= DD * 256) return;
    int c = idx >> 8, k = idx & 255;
    const float* Wl = blockIdx.y ? Wl2 : Wl1;
    const float* Wr = blockIdx.y ? Wr2 : Wr1;
    ushort* WTh = blockIdx.y ? WT2h : WT1h;
    ushort* WTl = blockIdx.y ? WT2l : WT1l;
    float v = (k < DD) ? Wl[k * DD + c] : Wr[(k - DD) * DD + c];
    ushort h = f2bf_rne(v);
    ushort lo = f2bf_rne(v - bf2f(h));
    WTh[idx] = h;
    WTl[idx] = lo;
}

// ====== Wout prep: WoT_hi/lo[c][k], c in [0,64), k in [0,128) ======
__global__ __launch_bounds__(256) void wosplit_kernel(const float* __restrict__ Wout,
                                                      ushort* __restrict__ WoTh,
                                                      ushort* __restrict__ WoTl) {
    int idx = blockIdx.x * 256 + threadIdx.x;   // c*128 + k
    if (idx >= CC * DD) return;
    int c = idx >> 7, k = idx & 127;
    float v = Wout[k * CC + c];
    ushort h = f2bf_rne(v);
    WoTh[idx] = h;
    WoTl[idx] = f2bf_rne(v - bf2f(h));
}

// ================= MFMA SAGE layer (all-bf16 A-side) =================
// out = relu([meanH | rootH] @ WT^T + bias); WT hi/lo keeps weight precision.
// PROJ: additionally compute out2 = h2 @ WoT^T + bout (f32) fully in-block:
//   stage h2 bf16 into the (freed) sB region as 4 k-slices of [64][40],
//   B-frags for WoT read directly from global (32KB, cache-hot).
template <bool PROJ>
__global__ __launch_bounds__(256) void layer_mfma_kernel(
    const ushort* __restrict__ meanH, const ushort* __restrict__ rootH,
    const ushort* __restrict__ WTh, const ushort* __restrict__ WTl,
    const float* __restrict__ bias, ushort* __restrict__ outH,
    const ushort* __restrict__ WoTh, const ushort* __restrict__ WoTl,
    const float* __restrict__ bout, float* __restrict__ outF, int n) {
    __shared__ ushort sAh[64][40];
    __shared__ ushort sB[2][128][40];
    const int tid = threadIdx.x;
    const int w = tid >> 6;
    const int l = tid & 63;
    const int row0 = blockIdx.x * 64;

    const int ar  = tid >> 2;            // A row 0..63
    const int akq = (tid & 3) * 8;       // A k offset within slice
    const int arowg = min(row0 + ar, n - 1);
    const int bc  = tid >> 1;            // B col 0..127
    const int bkh = (tid & 1) * 16;      // B k offset within slice

    const int arow = w * 16 + (l & 15);
    const int kb   = (l >> 4) * 8;
    const int lcol = l & 15;

    f32x4 acc[8];
    #pragma unroll
    for (int t = 0; t < 8; ++t) acc[t] = (f32x4){0.f, 0.f, 0.f, 0.f};

    for (int s = 0; s < 8; ++s) {
        const int k0 = s * 32;
        const ushort* Asrc = (s < 4) ? (meanH + (size_t)arowg * DD + k0)
                                     : (rootH + (size_t)arowg * DD + (k0 - DD));
        short8v ah_w = *(const short8v*)(Asrc + akq);
        const ushort* bhp = WTh + bc * 256 + k0 + bkh;
        const ushort* blp = WTl + bc * 256 + k0 + bkh;
        short8v bh0 = *(const short8v*)bhp;
        short8v bh1 = *(const short8v*)(bhp + 8);
        short8v bl0 = *(const short8v*)blp;
        short8v bl1 = *(const short8v*)(blp + 8);

        __syncthreads();
        *(short8v*)&sAh[ar][akq] = ah_w;
        *(short8v*)&sB[0][bc][bkh]     = bh0;
        *(short8v*)&sB[0][bc][bkh + 8] = bh1;
        *(short8v*)&sB[1][bc][bkh]     = bl0;
        *(short8v*)&sB[1][bc][bkh + 8] = bl1;
        __syncthreads();

        short8v ah = *(const short8v*)&sAh[arow][kb];
        #pragma unroll
        for (int t = 0; t < 8; ++t) {
            short8v bh = *(const short8v*)&sB[0][t * 16 + lcol][kb];
            short8v bl = *(const short8v*)&sB[1][t * 16 + lcol][kb];
            acc[t] = __builtin_amdgcn_mfma_f32_16x16x32_bf16(ah, bh, acc[t], 0, 0, 0);
            acc[t] = __builtin_amdgcn_mfma_f32_16x16x32_bf16(ah, bl, acc[t], 0, 0, 0);
        }
    }

    // C/D layout: col = t*16 + (lane&15), row = w*16 + 4*(lane>>4) + reg
    const int lrow0 = w * 16 + (l >> 4) * 4;
    if (!PROJ) {
        #pragma unroll
        for (int t = 0; t < 8; ++t) {
            const int col = t * 16 + lcol;
            const float b = bias[col];
            #pragma unroll
            for (int r = 0; r < 4; ++r) {
                int row = row0 + lrow0 + r;
                if (row < n)
                    outH[(size_t)row * DD + col] = f2bf_rne(fmaxf(acc[t][r] + b, 0.f));
            }
        }
    } else {
        // stage h2 bf16 into sB region as sH4[4][64][40] (k-slices of 32)
        ushort (*sH4)[64][40] = (ushort(*)[64][40])&sB[0][0][0];
        __syncthreads();   // all waves done reading sB from last slice
        #pragma unroll
        for (int t = 0; t < 8; ++t) {
            const int col = t * 16 + lcol;
            const float b = bias[col];
            #pragma unroll
            for (int r = 0; r < 4; ++r) {
                float o = fmaxf(acc[t][r] + b, 0.f);
                sH4[t >> 1][lrow0 + r][(t & 1) * 16 + lcol] = f2bf_rne(o);
            }
        }
        __syncthreads();
        f32x4 po[4];
        #pragma unroll
        for (int t = 0; t < 4; ++t) po[t] = (f32x4){0.f, 0.f, 0.f, 0.f};
        for (int kc = 0; kc < 4; ++kc) {
            short8v ah = *(const short8v*)&sH4[kc][arow][kb];
            #pragma unroll
            for (int t = 0; t < 4; ++t) {
                const int col = t * 16 + lcol;
                short8v bh = *(const short8v*)(WoTh + col * DD + kc * 32 + kb);
                short8v bl = *(const short8v*)(WoTl + col * DD + kc * 32 + kb);
                po[t] = __builtin_amdgcn_mfma_f32_16x16x32_bf16(ah, bh, po[t], 0, 0, 0);
                po[t] = __builtin_amdgcn_mfma_f32_16x16x32_bf16(ah, bl, po[t], 0, 0, 0);
            }
        }
        #pragma unroll
        for (int t = 0; t < 4; ++t) {
            const int col = t * 16 + lcol;
            const float b = bout[col];
            #pragma unroll
            for (int r = 0; r < 4; ++r) {
                int row = row0 + lrow0 + r;
                if (row < n) outF[(size_t)row * CC + col] = po[t][r] + b;
            }
        }
    }
}

extern "C" void kernel_launch(void* const* d_in, const int* in_sizes, int n_in,
                              void* d_out, int out_size, void* d_ws, size_t ws_size,
                              hipStream_t stream) {
    const float* x    = (const float*)d_in[0];
    const int*   ei   = (const int*)d_in[1];
    const float* W1l  = (const float*)d_in[2];
    const float* b1   = (const float*)d_in[3];
    const float* W1r  = (const float*)d_in[4];
    const float* W2l  = (const float*)d_in[5];
    const float* b2   = (const float*)d_in[6];
    const float* W2r  = (const float*)d_in[7];
    const float* Wout = (const float*)d_in[8];
    const float* bout = (const float*)d_in[9];
    float* out = (float*)d_out;
    const int n = in_sizes[0] / DD;       // 100000
    const int E = in_sizes[1] / 2;        // 1600000
    const size_t NP = (size_t)n * DD;

    const int NBUCK = (n + BKW - 1) / BKW;

    // workspace layout
    int* cnt   = (int*)d_ws;                              // 100352
    int* offs  = cnt + 100352;                            // 100352
    int* bcnt  = offs + 100352;                           // 256
    int* boffs = bcnt + 256;                              // 257 (pad 512)
    int* bcur  = boffs + 512;                             // 256
    int* csr   = bcur + 256;                              // E (pad)
    uint2* ebuf = (uint2*)(csr + 1600256);                // E pairs (12.8MB)
    ushort* xh  = (ushort*)ebuf;                          // union: n*128 bf16 (25.6MB)
    ushort* meanH = xh + NP;                              // n*128 bf16
    ushort* h1h = meanH + NP;                             // n*128 bf16
    ushort* WT1h = h1h + NP;                              // 128*256 each
    ushort* WT1l = WT1h + DD * 256;
    ushort* WT2h = WT1l + DD * 256;
    ushort* WT2l = WT2h + DD * 256;
    ushort* WoTh = WT2l + DD * 256;                       // 64*128 each
    ushort* WoTl = WoTh + CC * DD;

    hipMemsetAsync(bcnt, 0, sizeof(int) * 256, stream);
    bucket_cnt_kernel<<<(E + 8191) / 8192, 256, 0, stream>>>(ei, bcnt, E);
    bucket_scan_kernel<<<1, 256, 0, stream>>>(bcnt, boffs, bcur);
    binA_kernel<<<(E + NPB - 1) / NPB, 256, 0, stream>>>(ei, bcur, ebuf, E);
    binB2_kernel<<<NBUCK, 256, 0, stream>>>(ebuf, boffs, offs, cnt, csr, n);

    dim3 wgrid(DD, 2);
    wsplit_kernel<<<wgrid, 256, 0, stream>>>(W1l, W1r, W2l, W2r,
                                             WT1h, WT1l, WT2h, WT2l);
    wosplit_kernel<<<(CC * DD + 255) / 256, 256, 0, stream>>>(Wout, WoTh, WoTl);

    // ebuf dead now -> reuse region as xh
    xsplit_kernel<<<(n * DD / 8 + 255) / 256, 256, 0, stream>>>(x, xh, n * DD / 8);

    const int nblk = (n + 63) / 64;
    const int ablk = (n + 3) / 4;

    csr_agg4_kernel<<<ablk, 256, 0, stream>>>(xh, offs, cnt, csr, meanH, n);
    layer_mfma_kernel<false><<<nblk, 256, 0, stream>>>(
        meanH, xh, WT1h, WT1l, b1, h1h,
        (const ushort*)nullptr, (const ushort*)nullptr,
        (const float*)nullptr, (float*)nullptr, n);

    csr_agg4_kernel<<<ablk, 256, 0, stream>>>(h1h, offs, cnt, csr, meanH, n);
    layer_mfma_kernel<true><<<nblk, 256, 0, stream>>>(
        meanH, h1h, WT2h, WT2l, b2, (ushort*)nullptr,
        WoTh, WoTl, bout, out, n);
}